// Round 1
// baseline (78.951 us; speedup 1.0000x reference)
//
#include <hip/hip_runtime.h>
#include <math.h>

#define N_PTS 32768
#define LL    2048

// d_ws float offsets
#define KV_OFF    0          // [2][2048*6] interleaved k0,k1,k2,v0,v1,v2
#define KI_OFF    24576      // [2][3][3]  k_inter[m][k]
#define VI_OFF    24594      // [2][3][3]  v_inter[k][m]
#define KMAX_OFF  24612      // [2][3]     max_l |k_m|
#define PART_OFF  24618      // [256][12]  BN partials (sum, sumsq)
#define BNS_OFF   27690      // [6] scale
#define BNB_OFF   27696      // [6] shift

__device__ __forceinline__ float wave_reduce_sum(float v){
  #pragma unroll
  for (int off = 32; off; off >>= 1) v += __shfl_xor(v, off, 64);
  return v;
}
__device__ __forceinline__ float wave_reduce_max(float v){
  #pragma unroll
  for (int off = 32; off; off >>= 1) v = fmaxf(v, __shfl_xor(v, off, 64));
  return v;
}

// ---------------------------------------------------------------- prep ----
__global__ __launch_bounds__(256)
void prep_kernel(const float* __restrict__ curves,
                 const float* __restrict__ Wa,  const float* __restrict__ Wav,
                 const float* __restrict__ Wb,  const float* __restrict__ Wbv,
                 const float* __restrict__ Watt,
                 const float* __restrict__ Wpl, const float* __restrict__ bpl,
                 const float* __restrict__ Wpn, const float* __restrict__ bpn,
                 float* __restrict__ ws)
{
  const int b    = blockIdx.x;
  const int tid  = threadIdx.x;
  const int lane = tid & 63, wid = tid >> 6;

  __shared__ float att_s[3 * LL];     // 24 KB
  __shared__ float sred[4 * 36];
  __shared__ float m_nc[3], s_nc[3];

  float watt[6];
  #pragma unroll
  for (int c = 0; c < 6; c++) watt[c] = Watt[c];

  const float* cb = curves + b * 6 * 3 * LL;

  // S1: att[nc][l] = sum_c curves[b,c,nc,l] * Watt[c]
  for (int idx = tid; idx < 3 * LL; idx += 256) {
    int nc = idx >> 11, l = idx & (LL - 1);
    float s = 0.f;
    #pragma unroll
    for (int c = 0; c < 6; c++) s += cb[(c * 3 + nc) * LL + l] * watt[c];
    att_s[idx] = s;
  }
  __syncthreads();

  // S2a: max over L per nc
  {
    float pm[3] = {-1e30f, -1e30f, -1e30f};
    for (int l = tid; l < LL; l += 256) {
      #pragma unroll
      for (int nc = 0; nc < 3; nc++) pm[nc] = fmaxf(pm[nc], att_s[nc * LL + l]);
    }
    #pragma unroll
    for (int j = 0; j < 3; j++) pm[j] = wave_reduce_max(pm[j]);
    if (lane == 0) { for (int j = 0; j < 3; j++) sred[wid * 3 + j] = pm[j]; }
    __syncthreads();
    if (tid == 0) {
      for (int j = 0; j < 3; j++)
        m_nc[j] = fmaxf(fmaxf(sred[j], sred[3 + j]), fmaxf(sred[6 + j], sred[9 + j]));
    }
    __syncthreads();
  }
  // S2b: sum of exp over L per nc
  {
    float ps[3] = {0.f, 0.f, 0.f};
    for (int l = tid; l < LL; l += 256) {
      #pragma unroll
      for (int nc = 0; nc < 3; nc++) ps[nc] += __expf(att_s[nc * LL + l] - m_nc[nc]);
    }
    #pragma unroll
    for (int j = 0; j < 3; j++) ps[j] = wave_reduce_sum(ps[j]);
    if (lane == 0) { for (int j = 0; j < 3; j++) sred[wid * 3 + j] = ps[j]; }
    __syncthreads();
    if (tid == 0) {
      for (int j = 0; j < 3; j++)
        s_nc[j] = sred[j] + sred[3 + j] + sred[6 + j] + sred[9 + j];
    }
    __syncthreads();
  }

  // S3: partials for curver_inter (weighted by exp) and pbar (curves[0] mean)
  {
    float pv[36];
    #pragma unroll
    for (int j = 0; j < 36; j++) pv[j] = 0.f;
    for (int l = tid; l < LL; l += 256) {
      #pragma unroll
      for (int nc = 0; nc < 3; nc++) {
        float e = __expf(att_s[nc * LL + l] - m_nc[nc]);
        #pragma unroll
        for (int c = 0; c < 6; c++) {
          pv[c * 3 + nc]      += cb[(c * 3 + nc) * LL + l] * e;
          pv[18 + c * 3 + nc] += curves[(c * 3 + nc) * LL + l];   // batch 0
        }
      }
    }
    #pragma unroll
    for (int j = 0; j < 36; j++) pv[j] = wave_reduce_sum(pv[j]);
    if (lane == 0) { for (int j = 0; j < 36; j++) sred[wid * 36 + j] = pv[j]; }
    __syncthreads();
    if (tid == 0) {
      float tot[36];
      for (int j = 0; j < 36; j++)
        tot[j] = sred[j] + sred[36 + j] + sred[72 + j] + sred[108 + j];
      // p_l[c][m] = bpl[m] + sum_k Wpl[m,k] * mean_l(curves0[c,k,l])
      float gi[18];
      for (int c = 0; c < 6; c++) {
        for (int m = 0; m < 3; m++) {
          float pl = bpl[m];
          for (int k = 0; k < 3; k++)
            pl += Wpl[m * 3 + k] * (tot[18 + c * 3 + k] * (1.f / LL));
          gi[c * 3 + m] = tot[c * 3 + m] / s_nc[m] + pl;
        }
      }
      for (int m = 0; m < 3; m++)
        for (int k = 0; k < 3; k++) {
          float ki = 0.f, vi = 0.f;
          for (int c = 0; c < 6; c++) {
            ki += Wa [m * 6 + c] * gi[c * 3 + k];
            vi += Wav[m * 6 + c] * gi[c * 3 + k];
          }
          ws[KI_OFF + b * 9 + m * 3 + k] = ki;
          ws[VI_OFF + b * 9 + k * 3 + m] = vi;   // [k][m]
        }
    }
    __syncthreads();
  }

  // S5: per-l: softmax over nc, ga, k_intra/v_intra, |k| max
  {
    float wb_r[18], wbv_r[18];
    #pragma unroll
    for (int i = 0; i < 18; i++) { wb_r[i] = Wb[i]; wbv_r[i] = Wbv[i]; }
    float wn0 = (Wpn[0] + Wpn[3] + Wpn[6]) * (1.f / 3.f);
    float wn1 = (Wpn[1] + Wpn[4] + Wpn[7]) * (1.f / 3.f);
    float wn2 = (Wpn[2] + Wpn[5] + Wpn[8]) * (1.f / 3.f);
    float bnb = (bpn[0] + bpn[1] + bpn[2]) * (1.f / 3.f);
    float km[3] = {0.f, 0.f, 0.f};
    float* wkv = ws + KV_OFF + b * (LL * 6);

    for (int l = tid; l < LL; l += 256) {
      float a0 = att_s[l], a1 = att_s[LL + l], a2 = att_s[2 * LL + l];
      float mm = fmaxf(fmaxf(a0, a1), a2);
      float e0 = __expf(a0 - mm), e1 = __expf(a1 - mm), e2 = __expf(a2 - mm);
      float r = 1.f / (e0 + e1 + e2);
      float ga[6];
      #pragma unroll
      for (int c = 0; c < 6; c++) {
        const float* pb_ = cb + (c * 3) * LL + l;
        float intra = (pb_[0] * e0 + pb_[LL] * e1 + pb_[2 * LL] * e2) * r;
        const float* p0 = curves + (c * 3) * LL + l;   // batch 0
        float pn = p0[0] * wn0 + p0[LL] * wn1 + p0[2 * LL] * wn2 + bnb;
        ga[c] = intra + pn;
      }
      float k0 = 0, k1 = 0, k2 = 0, v0 = 0, v1 = 0, v2 = 0;
      #pragma unroll
      for (int c = 0; c < 6; c++) {
        k0 += wb_r[c] * ga[c];  k1 += wb_r[6 + c] * ga[c];  k2 += wb_r[12 + c] * ga[c];
        v0 += wbv_r[c] * ga[c]; v1 += wbv_r[6 + c] * ga[c]; v2 += wbv_r[12 + c] * ga[c];
      }
      float* o = wkv + l * 6;
      o[0] = k0; o[1] = k1; o[2] = k2; o[3] = v0; o[4] = v1; o[5] = v2;
      km[0] = fmaxf(km[0], fabsf(k0));
      km[1] = fmaxf(km[1], fabsf(k1));
      km[2] = fmaxf(km[2], fabsf(k2));
    }
    #pragma unroll
    for (int j = 0; j < 3; j++) km[j] = wave_reduce_max(km[j]);
    if (lane == 0) { for (int j = 0; j < 3; j++) sred[wid * 3 + j] = km[j]; }
    __syncthreads();
    if (tid == 0) {
      for (int j = 0; j < 3; j++)
        ws[KMAX_OFF + b * 3 + j] =
          fmaxf(fmaxf(sred[j], sred[3 + j]), fmaxf(sred[6 + j], sred[9 + j]));
    }
  }
}

// ---------------------------------------------------------------- main ----
__global__ __launch_bounds__(256)
void attn_kernel(const float* __restrict__ x,  const float* __restrict__ Wc,
                 const float* __restrict__ Wd, const float* __restrict__ lng,
                 const float* __restrict__ lnb,
                 float* __restrict__ ws, float* __restrict__ yout)
{
  __shared__ float4 kvs[3072];    // 48 KB: {k0,k1,k2,v0,v1,v2} x 2048, as float4 triplets per 2 keys
  __shared__ float  cp[48];
  const int tid = threadIdx.x;
  const int blk = blockIdx.x;
  const int row = blk * 256 + tid;
  const int b   = row >> 15;           // N = 32768
  const int n   = row & (N_PTS - 1);

  const float4* src = (const float4*)(ws + KV_OFF + b * (LL * 6));
  for (int i = tid; i < 3072; i += 256) kvs[i] = src[i];
  __syncthreads();

  const float* xb = x + (size_t)b * 6 * N_PTS + n;
  float xc[6];
  #pragma unroll
  for (int c = 0; c < 6; c++) xc[c] = xb[c * N_PTS];
  float q0 = 0, q1 = 0, q2 = 0;
  #pragma unroll
  for (int c = 0; c < 6; c++) {
    q0 += xc[c] * Wc[c]; q1 += xc[c] * Wc[6 + c]; q2 += xc[c] * Wc[12 + c];
  }
  const float KS = 1.4426950408889634f * 0.57735026918962576f;  // log2e / sqrt(3)
  float qs0 = q0 * KS, qs1 = q1 * KS, qs2 = q2 * KS;

  // feature_inter (3 keys, exact softmax)
  const float* ki = ws + KI_OFF + b * 9;
  const float* vi = ws + VI_OFF + b * 9;
  float sk0 = qs0 * ki[0] + qs1 * ki[3] + qs2 * ki[6];
  float sk1 = qs0 * ki[1] + qs1 * ki[4] + qs2 * ki[7];
  float sk2 = qs0 * ki[2] + qs1 * ki[5] + qs2 * ki[8];
  float mm  = fmaxf(fmaxf(sk0, sk1), sk2);
  float e0 = __builtin_amdgcn_exp2f(sk0 - mm);
  float e1 = __builtin_amdgcn_exp2f(sk1 - mm);
  float e2 = __builtin_amdgcn_exp2f(sk2 - mm);
  float rs = 1.f / (e0 + e1 + e2);
  float fi0 = (e0 * vi[0] + e1 * vi[3] + e2 * vi[6]) * rs;
  float fi1 = (e0 * vi[1] + e1 * vi[4] + e2 * vi[7]) * rs;
  float fi2 = (e0 * vi[2] + e1 * vi[5] + e2 * vi[8]) * rs;

  // upper bound on max_l s'_l  (common factor cancels in softmax ratio)
  const float* kmx = ws + KMAX_OFF + b * 3;
  float Mp = fabsf(qs0) * kmx[0] + fabsf(qs1) * kmx[1] + fabsf(qs2) * kmx[2];

  // single-pass softmax-weighted sum over L
  float d = 0.f, a0 = 0.f, a1 = 0.f, a2 = 0.f;
  #pragma unroll 4
  for (int j = 0; j < 1024; j++) {
    float4 A = kvs[3 * j], B = kvs[3 * j + 1], C = kvs[3 * j + 2];
    float s1 = fmaf(qs0, A.x, fmaf(qs1, A.y, fmaf(qs2, A.z, -Mp)));
    float ea = __builtin_amdgcn_exp2f(s1);
    d += ea; a0 = fmaf(ea, A.w, a0); a1 = fmaf(ea, B.x, a1); a2 = fmaf(ea, B.y, a2);
    float s2 = fmaf(qs0, B.z, fmaf(qs1, B.w, fmaf(qs2, C.x, -Mp)));
    float eb = __builtin_amdgcn_exp2f(s2);
    d += eb; a0 = fmaf(eb, C.y, a0); a1 = fmaf(eb, C.z, a1); a2 = fmaf(eb, C.w, a2);
  }
  float rinv = 1.f / d;
  float fa0 = a0 * rinv, fa1 = a1 * rinv, fa2 = a2 * rinv;

  // LayerNorm over 6
  float cf[6] = {fi0, fi1, fi2, fa0, fa1, fa2};
  float mu = (cf[0] + cf[1] + cf[2] + cf[3] + cf[4] + cf[5]) * (1.f / 6.f);
  float var = 0.f;
  #pragma unroll
  for (int i = 0; i < 6; i++) { float t = cf[i] - mu; var += t * t; }
  var *= (1.f / 6.f);
  float rn = rsqrtf(var + 1e-5f);
  float cfn[6];
  #pragma unroll
  for (int i = 0; i < 6; i++) cfn[i] = (cf[i] - mu) * rn * lng[i] + lnb[i];

  // y = Wd @ cfn ; store pre-BN into d_out
  float y[6];
  #pragma unroll
  for (int o = 0; o < 6; o++) {
    float s = 0.f;
    #pragma unroll
    for (int c = 0; c < 6; c++) s += Wd[o * 6 + c] * cfn[c];
    y[o] = s;
    yout[(size_t)b * (6 * N_PTS) + o * N_PTS + n] = s;
  }

  // deterministic BN partials (per block)
  float v12[12];
  #pragma unroll
  for (int o = 0; o < 6; o++) { v12[o] = y[o]; v12[6 + o] = y[o] * y[o]; }
  #pragma unroll
  for (int j = 0; j < 12; j++) v12[j] = wave_reduce_sum(v12[j]);
  const int lane = tid & 63, wid = tid >> 6;
  if (lane == 0) { for (int j = 0; j < 12; j++) cp[wid * 12 + j] = v12[j]; }
  __syncthreads();
  if (tid == 0) {
    float* part = ws + PART_OFF + blk * 12;
    for (int j = 0; j < 12; j++)
      part[j] = cp[j] + cp[12 + j] + cp[24 + j] + cp[36 + j];
  }
}

// ------------------------------------------------------------- bn stats ---
__global__ __launch_bounds__(256)
void bnstats_kernel(const float* __restrict__ bng, const float* __restrict__ bnbt,
                    float* __restrict__ ws)
{
  __shared__ float cp[48];
  const int tid = threadIdx.x;
  const float* part = ws + PART_OFF;
  float v[12];
  #pragma unroll
  for (int j = 0; j < 12; j++) v[j] = part[tid * 12 + j];
  #pragma unroll
  for (int j = 0; j < 12; j++) v[j] = wave_reduce_sum(v[j]);
  const int lane = tid & 63, wid = tid >> 6;
  if (lane == 0) { for (int j = 0; j < 12; j++) cp[wid * 12 + j] = v[j]; }
  __syncthreads();
  if (tid == 0) {
    const float inv = 1.f / 65536.f;   // B * N
    for (int o = 0; o < 6; o++) {
      float s1 = cp[o] + cp[12 + o] + cp[24 + o] + cp[36 + o];
      float s2 = cp[6 + o] + cp[18 + o] + cp[30 + o] + cp[42 + o];
      float mean = s1 * inv;
      float varr = s2 * inv - mean * mean;
      float sc = bng[o] * rsqrtf(varr + 1e-5f);
      ws[BNS_OFF + o] = sc;
      ws[BNB_OFF + o] = bnbt[o] - mean * sc;
    }
  }
}

// ------------------------------------------------------------- finalize ---
__global__ __launch_bounds__(256)
void final_kernel(const float* __restrict__ x, const float* __restrict__ ws,
                  float* __restrict__ out)
{
  const int i = blockIdx.x * 256 + threadIdx.x;   // 393216 total
  const int ch = (i >> 15) % 6;
  float v = out[i] * ws[BNS_OFF + ch] + ws[BNB_OFF + ch] + x[i];
  out[i] = v >= 0.f ? v : 0.2f * v;
}

// ---------------------------------------------------------------- launch --
extern "C" void kernel_launch(void* const* d_in, const int* in_sizes, int n_in,
                              void* d_out, int out_size, void* d_ws, size_t ws_size,
                              hipStream_t stream)
{
  const float* x      = (const float*)d_in[0];
  const float* curves = (const float*)d_in[1];
  const float* Wa     = (const float*)d_in[2];
  const float* Wav    = (const float*)d_in[3];
  const float* Wb     = (const float*)d_in[4];
  const float* Wbv    = (const float*)d_in[5];
  const float* Wc     = (const float*)d_in[6];
  const float* Wd     = (const float*)d_in[7];
  const float* bng    = (const float*)d_in[8];
  const float* bnbt   = (const float*)d_in[9];
  const float* Watt   = (const float*)d_in[10];
  const float* lng    = (const float*)d_in[11];
  const float* lnbt   = (const float*)d_in[12];
  const float* Wpl    = (const float*)d_in[13];
  const float* bpl    = (const float*)d_in[14];
  const float* Wpn    = (const float*)d_in[15];
  const float* bpn    = (const float*)d_in[16];
  float* out = (float*)d_out;
  float* ws  = (float*)d_ws;

  prep_kernel<<<2, 256, 0, stream>>>(curves, Wa, Wav, Wb, Wbv, Watt,
                                     Wpl, bpl, Wpn, bpn, ws);
  attn_kernel<<<256, 256, 0, stream>>>(x, Wc, Wd, lng, lnbt, ws, out);
  bnstats_kernel<<<1, 256, 0, stream>>>(bng, bnbt, ws);
  final_kernel<<<1536, 256, 0, stream>>>(x, ws, out);
}

// Round 2
// 68.299 us; speedup vs baseline: 1.1560x; 1.1560x over previous
//
#include <hip/hip_runtime.h>
#include <math.h>

#define N_PTS 32768
#define LL    2048

// d_ws float offsets
#define KV_OFF    0          // [2][2048*6] interleaved k0,k1,k2,v0,v1,v2
#define KI_OFF    24576      // [2][3][3]  k_inter[m][k]
#define VI_OFF    24594      // [2][3][3]  v_inter[k][m]
#define KMAX_OFF  24612      // [2][3]     max_l |k_m|
#define PART_OFF  24618      // [1024][12] BN partials (sum, sumsq)
#define BNS_OFF   36906      // [6] scale
#define BNB_OFF   36912      // [6] shift

__device__ __forceinline__ float wave_reduce_sum(float v){
  #pragma unroll
  for (int off = 32; off; off >>= 1) v += __shfl_xor(v, off, 64);
  return v;
}
__device__ __forceinline__ float wave_reduce_max(float v){
  #pragma unroll
  for (int off = 32; off; off >>= 1) v = fmaxf(v, __shfl_xor(v, off, 64));
  return v;
}

// ---------------------------------------------------------------- prep ----
__global__ __launch_bounds__(256)
void prep_kernel(const float* __restrict__ curves,
                 const float* __restrict__ Wa,  const float* __restrict__ Wav,
                 const float* __restrict__ Wb,  const float* __restrict__ Wbv,
                 const float* __restrict__ Watt,
                 const float* __restrict__ Wpl, const float* __restrict__ bpl,
                 const float* __restrict__ Wpn, const float* __restrict__ bpn,
                 float* __restrict__ ws)
{
  const int b    = blockIdx.x;
  const int tid  = threadIdx.x;
  const int lane = tid & 63, wid = tid >> 6;

  __shared__ float att_s[3 * LL];     // 24 KB
  __shared__ float sred[4 * 36];
  __shared__ float m_nc[3], s_nc[3];

  float watt[6];
  #pragma unroll
  for (int c = 0; c < 6; c++) watt[c] = Watt[c];

  const float* cb = curves + b * 6 * 3 * LL;

  // S1: att[nc][l] = sum_c curves[b,c,nc,l] * Watt[c]
  for (int idx = tid; idx < 3 * LL; idx += 256) {
    int nc = idx >> 11, l = idx & (LL - 1);
    float s = 0.f;
    #pragma unroll
    for (int c = 0; c < 6; c++) s += cb[(c * 3 + nc) * LL + l] * watt[c];
    att_s[idx] = s;
  }
  __syncthreads();

  // S2a: max over L per nc
  {
    float pm[3] = {-1e30f, -1e30f, -1e30f};
    for (int l = tid; l < LL; l += 256) {
      #pragma unroll
      for (int nc = 0; nc < 3; nc++) pm[nc] = fmaxf(pm[nc], att_s[nc * LL + l]);
    }
    #pragma unroll
    for (int j = 0; j < 3; j++) pm[j] = wave_reduce_max(pm[j]);
    if (lane == 0) { for (int j = 0; j < 3; j++) sred[wid * 3 + j] = pm[j]; }
    __syncthreads();
    if (tid == 0) {
      for (int j = 0; j < 3; j++)
        m_nc[j] = fmaxf(fmaxf(sred[j], sred[3 + j]), fmaxf(sred[6 + j], sred[9 + j]));
    }
    __syncthreads();
  }
  // S2b: sum of exp over L per nc
  {
    float ps[3] = {0.f, 0.f, 0.f};
    for (int l = tid; l < LL; l += 256) {
      #pragma unroll
      for (int nc = 0; nc < 3; nc++) ps[nc] += __expf(att_s[nc * LL + l] - m_nc[nc]);
    }
    #pragma unroll
    for (int j = 0; j < 3; j++) ps[j] = wave_reduce_sum(ps[j]);
    if (lane == 0) { for (int j = 0; j < 3; j++) sred[wid * 3 + j] = ps[j]; }
    __syncthreads();
    if (tid == 0) {
      for (int j = 0; j < 3; j++)
        s_nc[j] = sred[j] + sred[3 + j] + sred[6 + j] + sred[9 + j];
    }
    __syncthreads();
  }

  // S3: partials for curver_inter (weighted by exp) and pbar (curves[0] mean)
  {
    float pv[36];
    #pragma unroll
    for (int j = 0; j < 36; j++) pv[j] = 0.f;
    for (int l = tid; l < LL; l += 256) {
      #pragma unroll
      for (int nc = 0; nc < 3; nc++) {
        float e = __expf(att_s[nc * LL + l] - m_nc[nc]);
        #pragma unroll
        for (int c = 0; c < 6; c++) {
          pv[c * 3 + nc]      += cb[(c * 3 + nc) * LL + l] * e;
          pv[18 + c * 3 + nc] += curves[(c * 3 + nc) * LL + l];   // batch 0
        }
      }
    }
    #pragma unroll
    for (int j = 0; j < 36; j++) pv[j] = wave_reduce_sum(pv[j]);
    if (lane == 0) { for (int j = 0; j < 36; j++) sred[wid * 36 + j] = pv[j]; }
    __syncthreads();
    if (tid == 0) {
      float tot[36];
      for (int j = 0; j < 36; j++)
        tot[j] = sred[j] + sred[36 + j] + sred[72 + j] + sred[108 + j];
      // p_l[c][m] = bpl[m] + sum_k Wpl[m,k] * mean_l(curves0[c,k,l])
      float gi[18];
      for (int c = 0; c < 6; c++) {
        for (int m = 0; m < 3; m++) {
          float pl = bpl[m];
          for (int k = 0; k < 3; k++)
            pl += Wpl[m * 3 + k] * (tot[18 + c * 3 + k] * (1.f / LL));
          gi[c * 3 + m] = tot[c * 3 + m] / s_nc[m] + pl;
        }
      }
      for (int m = 0; m < 3; m++)
        for (int k = 0; k < 3; k++) {
          float ki = 0.f, vi = 0.f;
          for (int c = 0; c < 6; c++) {
            ki += Wa [m * 6 + c] * gi[c * 3 + k];
            vi += Wav[m * 6 + c] * gi[c * 3 + k];
          }
          ws[KI_OFF + b * 9 + m * 3 + k] = ki;
          ws[VI_OFF + b * 9 + k * 3 + m] = vi;   // [k][m]
        }
    }
    __syncthreads();
  }

  // S5: per-l: softmax over nc, ga, k_intra/v_intra, |k| max
  {
    float wb_r[18], wbv_r[18];
    #pragma unroll
    for (int i = 0; i < 18; i++) { wb_r[i] = Wb[i]; wbv_r[i] = Wbv[i]; }
    float wn0 = (Wpn[0] + Wpn[3] + Wpn[6]) * (1.f / 3.f);
    float wn1 = (Wpn[1] + Wpn[4] + Wpn[7]) * (1.f / 3.f);
    float wn2 = (Wpn[2] + Wpn[5] + Wpn[8]) * (1.f / 3.f);
    float bnb = (bpn[0] + bpn[1] + bpn[2]) * (1.f / 3.f);
    float km[3] = {0.f, 0.f, 0.f};
    float* wkv = ws + KV_OFF + b * (LL * 6);

    for (int l = tid; l < LL; l += 256) {
      float a0 = att_s[l], a1 = att_s[LL + l], a2 = att_s[2 * LL + l];
      float mm = fmaxf(fmaxf(a0, a1), a2);
      float e0 = __expf(a0 - mm), e1 = __expf(a1 - mm), e2 = __expf(a2 - mm);
      float r = 1.f / (e0 + e1 + e2);
      float ga[6];
      #pragma unroll
      for (int c = 0; c < 6; c++) {
        const float* pb_ = cb + (c * 3) * LL + l;
        float intra = (pb_[0] * e0 + pb_[LL] * e1 + pb_[2 * LL] * e2) * r;
        const float* p0 = curves + (c * 3) * LL + l;   // batch 0
        float pn = p0[0] * wn0 + p0[LL] * wn1 + p0[2 * LL] * wn2 + bnb;
        ga[c] = intra + pn;
      }
      float k0 = 0, k1 = 0, k2 = 0, v0 = 0, v1 = 0, v2 = 0;
      #pragma unroll
      for (int c = 0; c < 6; c++) {
        k0 += wb_r[c] * ga[c];  k1 += wb_r[6 + c] * ga[c];  k2 += wb_r[12 + c] * ga[c];
        v0 += wbv_r[c] * ga[c]; v1 += wbv_r[6 + c] * ga[c]; v2 += wbv_r[12 + c] * ga[c];
      }
      float* o = wkv + l * 6;
      o[0] = k0; o[1] = k1; o[2] = k2; o[3] = v0; o[4] = v1; o[5] = v2;
      km[0] = fmaxf(km[0], fabsf(k0));
      km[1] = fmaxf(km[1], fabsf(k1));
      km[2] = fmaxf(km[2], fabsf(k2));
    }
    #pragma unroll
    for (int j = 0; j < 3; j++) km[j] = wave_reduce_max(km[j]);
    if (lane == 0) { for (int j = 0; j < 3; j++) sred[wid * 3 + j] = km[j]; }
    __syncthreads();
    if (tid == 0) {
      for (int j = 0; j < 3; j++)
        ws[KMAX_OFF + b * 3 + j] =
          fmaxf(fmaxf(sred[j], sred[3 + j]), fmaxf(sred[6 + j], sred[9 + j]));
    }
  }
}

// ---------------------------------------------------------------- main ----
// Each block: 64 rows. Each thread: 2 rows x 1/8 of L (seg = tid&7).
// Segments staggered by one float4 in LDS -> conflict-free 8-address reads.
__global__ __launch_bounds__(256)
void attn_kernel(const float* __restrict__ x,  const float* __restrict__ Wc,
                 const float* __restrict__ Wd, const float* __restrict__ lng,
                 const float* __restrict__ lnb,
                 float* __restrict__ ws, float* __restrict__ yout)
{
  __shared__ float4 kvs[8 * 385];   // 49280 B
  __shared__ float  cp[48];
  const int tid = threadIdx.x;
  const int blk = blockIdx.x;           // 1024 blocks
  const int seg = tid & 7;
  const int rp  = tid >> 3;             // 0..31
  const int r0  = blk * 64 + rp * 2;    // global row (even)
  const int b   = r0 >> 15;
  const int n0  = r0 & (N_PTS - 1);

  const float4* src = (const float4*)(ws + KV_OFF + b * (LL * 6));
  for (int i = tid; i < 3072; i += 256) {
    int s = i / 384;          // 384 float4 per segment
    int t = i - s * 384;
    kvs[s * 385 + t] = src[i];
  }
  __syncthreads();

  // q for 2 consecutive rows
  const float* xb = x + (size_t)b * 6 * N_PTS + n0;
  float q00 = 0, q01 = 0, q02 = 0, q10 = 0, q11 = 0, q12 = 0;
  #pragma unroll
  for (int c = 0; c < 6; c++) {
    float2 xv = *(const float2*)(xb + c * N_PTS);
    q00 = fmaf(xv.x, Wc[c], q00); q01 = fmaf(xv.x, Wc[6 + c], q01); q02 = fmaf(xv.x, Wc[12 + c], q02);
    q10 = fmaf(xv.y, Wc[c], q10); q11 = fmaf(xv.y, Wc[6 + c], q11); q12 = fmaf(xv.y, Wc[12 + c], q12);
  }
  const float KS = 1.4426950408889634f * 0.57735026918962576f;  // log2e / sqrt(3)
  float qs00 = q00 * KS, qs01 = q01 * KS, qs02 = q02 * KS;
  float qs10 = q10 * KS, qs11 = q11 * KS, qs12 = q12 * KS;

  const float* kmx = ws + KMAX_OFF + b * 3;
  float Mp0 = fabsf(qs00) * kmx[0] + fabsf(qs01) * kmx[1] + fabsf(qs02) * kmx[2];
  float Mp1 = fabsf(qs10) * kmx[0] + fabsf(qs11) * kmx[1] + fabsf(qs12) * kmx[2];

  // single-pass softmax-weighted sums over this thread's 256 keys
  float d0 = 0, p00 = 0, p01 = 0, p02 = 0;
  float d1 = 0, p10 = 0, p11 = 0, p12 = 0;
  const float4* kp = &kvs[seg * 385];
  #pragma unroll 4
  for (int j = 0; j < 128; j++) {
    float4 A = kp[3 * j], B = kp[3 * j + 1], C = kp[3 * j + 2];
    // key a: k=(A.x,A.y,A.z) v=(A.w,B.x,B.y)
    float sa0 = fmaf(qs00, A.x, fmaf(qs01, A.y, fmaf(qs02, A.z, -Mp0)));
    float sa1 = fmaf(qs10, A.x, fmaf(qs11, A.y, fmaf(qs12, A.z, -Mp1)));
    float ea0 = __builtin_amdgcn_exp2f(sa0);
    float ea1 = __builtin_amdgcn_exp2f(sa1);
    d0 += ea0; p00 = fmaf(ea0, A.w, p00); p01 = fmaf(ea0, B.x, p01); p02 = fmaf(ea0, B.y, p02);
    d1 += ea1; p10 = fmaf(ea1, A.w, p10); p11 = fmaf(ea1, B.x, p11); p12 = fmaf(ea1, B.y, p12);
    // key b: k=(B.z,B.w,C.x) v=(C.y,C.z,C.w)
    float sb0 = fmaf(qs00, B.z, fmaf(qs01, B.w, fmaf(qs02, C.x, -Mp0)));
    float sb1 = fmaf(qs10, B.z, fmaf(qs11, B.w, fmaf(qs12, C.x, -Mp1)));
    float eb0 = __builtin_amdgcn_exp2f(sb0);
    float eb1 = __builtin_amdgcn_exp2f(sb1);
    d0 += eb0; p00 = fmaf(eb0, C.y, p00); p01 = fmaf(eb0, C.z, p01); p02 = fmaf(eb0, C.w, p02);
    d1 += eb1; p10 = fmaf(eb1, C.y, p10); p11 = fmaf(eb1, C.z, p11); p12 = fmaf(eb1, C.w, p12);
  }

  // butterfly-combine across the 8 segments (Mp is seg-independent)
  #pragma unroll
  for (int m = 1; m <= 4; m <<= 1) {
    d0  += __shfl_xor(d0,  m, 64); p00 += __shfl_xor(p00, m, 64);
    p01 += __shfl_xor(p01, m, 64); p02 += __shfl_xor(p02, m, 64);
    d1  += __shfl_xor(d1,  m, 64); p10 += __shfl_xor(p10, m, 64);
    p11 += __shfl_xor(p11, m, 64); p12 += __shfl_xor(p12, m, 64);
  }

  float v12[12];
  #pragma unroll
  for (int j = 0; j < 12; j++) v12[j] = 0.f;

  if (seg == 0) {
    const float* ki = ws + KI_OFF + b * 9;
    const float* vi = ws + VI_OFF + b * 9;
    #pragma unroll
    for (int r = 0; r < 2; r++) {
      float a0 = r ? qs10 : qs00, a1 = r ? qs11 : qs01, a2 = r ? qs12 : qs02;
      float dd = r ? d1 : d0;
      float w0 = r ? p10 : p00, w1 = r ? p11 : p01, w2 = r ? p12 : p02;
      // feature_inter (3 keys, exact softmax)
      float sk0 = a0 * ki[0] + a1 * ki[3] + a2 * ki[6];
      float sk1 = a0 * ki[1] + a1 * ki[4] + a2 * ki[7];
      float sk2 = a0 * ki[2] + a1 * ki[5] + a2 * ki[8];
      float mm  = fmaxf(fmaxf(sk0, sk1), sk2);
      float e0 = __builtin_amdgcn_exp2f(sk0 - mm);
      float e1 = __builtin_amdgcn_exp2f(sk1 - mm);
      float e2 = __builtin_amdgcn_exp2f(sk2 - mm);
      float rs = 1.f / (e0 + e1 + e2);
      float fi0 = (e0 * vi[0] + e1 * vi[3] + e2 * vi[6]) * rs;
      float fi1 = (e0 * vi[1] + e1 * vi[4] + e2 * vi[7]) * rs;
      float fi2 = (e0 * vi[2] + e1 * vi[5] + e2 * vi[8]) * rs;
      float rinv = 1.f / dd;
      float cf[6] = { fi0, fi1, fi2, w0 * rinv, w1 * rinv, w2 * rinv };

      float mu = (cf[0] + cf[1] + cf[2] + cf[3] + cf[4] + cf[5]) * (1.f / 6.f);
      float var = 0.f;
      #pragma unroll
      for (int i = 0; i < 6; i++) { float t = cf[i] - mu; var += t * t; }
      var *= (1.f / 6.f);
      float rn = rsqrtf(var + 1e-5f);
      float cfn[6];
      #pragma unroll
      for (int i = 0; i < 6; i++) cfn[i] = (cf[i] - mu) * rn * lng[i] + lnb[i];

      #pragma unroll
      for (int o = 0; o < 6; o++) {
        float s = 0.f;
        #pragma unroll
        for (int c = 0; c < 6; c++) s += Wd[o * 6 + c] * cfn[c];
        yout[(size_t)b * (6 * N_PTS) + o * N_PTS + n0 + r] = s;
        v12[o] += s; v12[6 + o] += s * s;
      }
    }
  }

  // deterministic BN partials (per block)
  #pragma unroll
  for (int j = 0; j < 12; j++) v12[j] = wave_reduce_sum(v12[j]);
  const int lane = tid & 63, wid = tid >> 6;
  if (lane == 0) { for (int j = 0; j < 12; j++) cp[wid * 12 + j] = v12[j]; }
  __syncthreads();
  if (tid == 0) {
    float* part = ws + PART_OFF + blk * 12;
    for (int j = 0; j < 12; j++)
      part[j] = cp[j] + cp[12 + j] + cp[24 + j] + cp[36 + j];
  }
}

// ------------------------------------------------------------- bn stats ---
__global__ __launch_bounds__(256)
void bnstats_kernel(const float* __restrict__ bng, const float* __restrict__ bnbt,
                    float* __restrict__ ws)
{
  __shared__ float cp[48];
  const int tid = threadIdx.x;
  const float* part = ws + PART_OFF;
  float v[12];
  #pragma unroll
  for (int j = 0; j < 12; j++)
    v[j] = part[tid * 12 + j] + part[(tid + 256) * 12 + j]
         + part[(tid + 512) * 12 + j] + part[(tid + 768) * 12 + j];
  #pragma unroll
  for (int j = 0; j < 12; j++) v[j] = wave_reduce_sum(v[j]);
  const int lane = tid & 63, wid = tid >> 6;
  if (lane == 0) { for (int j = 0; j < 12; j++) cp[wid * 12 + j] = v[j]; }
  __syncthreads();
  if (tid == 0) {
    const float inv = 1.f / 65536.f;   // B * N
    for (int o = 0; o < 6; o++) {
      float s1 = cp[o] + cp[12 + o] + cp[24 + o] + cp[36 + o];
      float s2 = cp[6 + o] + cp[18 + o] + cp[30 + o] + cp[42 + o];
      float mean = s1 * inv;
      float varr = s2 * inv - mean * mean;
      float sc = bng[o] * rsqrtf(varr + 1e-5f);
      ws[BNS_OFF + o] = sc;
      ws[BNB_OFF + o] = bnbt[o] - mean * sc;
    }
  }
}

// ------------------------------------------------------------- finalize ---
__global__ __launch_bounds__(256)
void final_kernel(const float* __restrict__ x, const float* __restrict__ ws,
                  float* __restrict__ out)
{
  const int i = blockIdx.x * 256 + threadIdx.x;   // 393216 total
  const int ch = (i >> 15) % 6;
  float v = out[i] * ws[BNS_OFF + ch] + ws[BNB_OFF + ch] + x[i];
  out[i] = v >= 0.f ? v : 0.2f * v;
}

// ---------------------------------------------------------------- launch --
extern "C" void kernel_launch(void* const* d_in, const int* in_sizes, int n_in,
                              void* d_out, int out_size, void* d_ws, size_t ws_size,
                              hipStream_t stream)
{
  const float* x      = (const float*)d_in[0];
  const float* curves = (const float*)d_in[1];
  const float* Wa     = (const float*)d_in[2];
  const float* Wav    = (const float*)d_in[3];
  const float* Wb     = (const float*)d_in[4];
  const float* Wbv    = (const float*)d_in[5];
  const float* Wc     = (const float*)d_in[6];
  const float* Wd     = (const float*)d_in[7];
  const float* bng    = (const float*)d_in[8];
  const float* bnbt   = (const float*)d_in[9];
  const float* Watt   = (const float*)d_in[10];
  const float* lng    = (const float*)d_in[11];
  const float* lnbt   = (const float*)d_in[12];
  const float* Wpl    = (const float*)d_in[13];
  const float* bpl    = (const float*)d_in[14];
  const float* Wpn    = (const float*)d_in[15];
  const float* bpn    = (const float*)d_in[16];
  float* out = (float*)d_out;
  float* ws  = (float*)d_ws;

  prep_kernel<<<2, 256, 0, stream>>>(curves, Wa, Wav, Wb, Wbv, Watt,
                                     Wpl, bpl, Wpn, bpn, ws);
  attn_kernel<<<1024, 256, 0, stream>>>(x, Wc, Wd, lng, lnbt, ws, out);
  bnstats_kernel<<<1, 256, 0, stream>>>(bng, bnbt, ws);
  final_kernel<<<1536, 256, 0, stream>>>(x, ws, out);
}

// Round 3
// 67.201 us; speedup vs baseline: 1.1748x; 1.0163x over previous
//
#include <hip/hip_runtime.h>
#include <math.h>

#define N_PTS 32768
#define LL    2048

// d_ws float offsets
#define KV_OFF    0          // [2][2048*6] interleaved k0,k1,k2,v0,v1,v2
#define KI_OFF    24576      // [2][3][3]  k_inter[m][k]
#define VI_OFF    24594      // [2][3][3]  v_inter[k][m]
#define KMAX_OFF  24612      // [2][3]     max_l |k_m|
#define PART_OFF  24618      // [512][12]  BN partials (sum, sumsq)
#define BNS_OFF   30762      // [6] scale
#define BNB_OFF   30768      // [6] shift

__device__ __forceinline__ float wave_reduce_sum(float v){
  #pragma unroll
  for (int off = 32; off; off >>= 1) v += __shfl_xor(v, off, 64);
  return v;
}
__device__ __forceinline__ float wave_reduce_max(float v){
  #pragma unroll
  for (int off = 32; off; off >>= 1) v = fmaxf(v, __shfl_xor(v, off, 64));
  return v;
}

// ---------------------------------------------------------------- prep ----
__global__ __launch_bounds__(256)
void prep_kernel(const float* __restrict__ curves,
                 const float* __restrict__ Wa,  const float* __restrict__ Wav,
                 const float* __restrict__ Wb,  const float* __restrict__ Wbv,
                 const float* __restrict__ Watt,
                 const float* __restrict__ Wpl, const float* __restrict__ bpl,
                 const float* __restrict__ Wpn, const float* __restrict__ bpn,
                 float* __restrict__ ws)
{
  const int b    = blockIdx.x;
  const int tid  = threadIdx.x;
  const int lane = tid & 63, wid = tid >> 6;

  __shared__ float att_s[3 * LL];     // 24 KB
  __shared__ float sred[4 * 36];
  __shared__ float m_nc[3], s_nc[3];

  float watt[6];
  #pragma unroll
  for (int c = 0; c < 6; c++) watt[c] = Watt[c];

  const float* cb = curves + b * 6 * 3 * LL;

  // S1: att[nc][l] = sum_c curves[b,c,nc,l] * Watt[c]
  for (int idx = tid; idx < 3 * LL; idx += 256) {
    int nc = idx >> 11, l = idx & (LL - 1);
    float s = 0.f;
    #pragma unroll
    for (int c = 0; c < 6; c++) s += cb[(c * 3 + nc) * LL + l] * watt[c];
    att_s[idx] = s;
  }
  __syncthreads();

  // S2a: max over L per nc
  {
    float pm[3] = {-1e30f, -1e30f, -1e30f};
    for (int l = tid; l < LL; l += 256) {
      #pragma unroll
      for (int nc = 0; nc < 3; nc++) pm[nc] = fmaxf(pm[nc], att_s[nc * LL + l]);
    }
    #pragma unroll
    for (int j = 0; j < 3; j++) pm[j] = wave_reduce_max(pm[j]);
    if (lane == 0) { for (int j = 0; j < 3; j++) sred[wid * 3 + j] = pm[j]; }
    __syncthreads();
    if (tid == 0) {
      for (int j = 0; j < 3; j++)
        m_nc[j] = fmaxf(fmaxf(sred[j], sred[3 + j]), fmaxf(sred[6 + j], sred[9 + j]));
    }
    __syncthreads();
  }
  // S2b: sum of exp over L per nc
  {
    float ps[3] = {0.f, 0.f, 0.f};
    for (int l = tid; l < LL; l += 256) {
      #pragma unroll
      for (int nc = 0; nc < 3; nc++) ps[nc] += __expf(att_s[nc * LL + l] - m_nc[nc]);
    }
    #pragma unroll
    for (int j = 0; j < 3; j++) ps[j] = wave_reduce_sum(ps[j]);
    if (lane == 0) { for (int j = 0; j < 3; j++) sred[wid * 3 + j] = ps[j]; }
    __syncthreads();
    if (tid == 0) {
      for (int j = 0; j < 3; j++)
        s_nc[j] = sred[j] + sred[3 + j] + sred[6 + j] + sred[9 + j];
    }
    __syncthreads();
  }

  // S3: partials for curver_inter (weighted by exp) and pbar (curves[0] mean)
  {
    float pv[36];
    #pragma unroll
    for (int j = 0; j < 36; j++) pv[j] = 0.f;
    for (int l = tid; l < LL; l += 256) {
      #pragma unroll
      for (int nc = 0; nc < 3; nc++) {
        float e = __expf(att_s[nc * LL + l] - m_nc[nc]);
        #pragma unroll
        for (int c = 0; c < 6; c++) {
          pv[c * 3 + nc]      += cb[(c * 3 + nc) * LL + l] * e;
          pv[18 + c * 3 + nc] += curves[(c * 3 + nc) * LL + l];   // batch 0
        }
      }
    }
    #pragma unroll
    for (int j = 0; j < 36; j++) pv[j] = wave_reduce_sum(pv[j]);
    if (lane == 0) { for (int j = 0; j < 36; j++) sred[wid * 36 + j] = pv[j]; }
    __syncthreads();
    if (tid == 0) {
      float tot[36];
      for (int j = 0; j < 36; j++)
        tot[j] = sred[j] + sred[36 + j] + sred[72 + j] + sred[108 + j];
      // p_l[c][m] = bpl[m] + sum_k Wpl[m,k] * mean_l(curves0[c,k,l])
      float gi[18];
      for (int c = 0; c < 6; c++) {
        for (int m = 0; m < 3; m++) {
          float pl = bpl[m];
          for (int k = 0; k < 3; k++)
            pl += Wpl[m * 3 + k] * (tot[18 + c * 3 + k] * (1.f / LL));
          gi[c * 3 + m] = tot[c * 3 + m] / s_nc[m] + pl;
        }
      }
      for (int m = 0; m < 3; m++)
        for (int k = 0; k < 3; k++) {
          float ki = 0.f, vi = 0.f;
          for (int c = 0; c < 6; c++) {
            ki += Wa [m * 6 + c] * gi[c * 3 + k];
            vi += Wav[m * 6 + c] * gi[c * 3 + k];
          }
          ws[KI_OFF + b * 9 + m * 3 + k] = ki;
          ws[VI_OFF + b * 9 + k * 3 + m] = vi;   // [k][m]
        }
    }
    __syncthreads();
  }

  // S5: per-l: softmax over nc, ga, k_intra/v_intra, |k| max
  {
    float wb_r[18], wbv_r[18];
    #pragma unroll
    for (int i = 0; i < 18; i++) { wb_r[i] = Wb[i]; wbv_r[i] = Wbv[i]; }
    float wn0 = (Wpn[0] + Wpn[3] + Wpn[6]) * (1.f / 3.f);
    float wn1 = (Wpn[1] + Wpn[4] + Wpn[7]) * (1.f / 3.f);
    float wn2 = (Wpn[2] + Wpn[5] + Wpn[8]) * (1.f / 3.f);
    float bnb = (bpn[0] + bpn[1] + bpn[2]) * (1.f / 3.f);
    float km[3] = {0.f, 0.f, 0.f};
    float* wkv = ws + KV_OFF + b * (LL * 6);

    for (int l = tid; l < LL; l += 256) {
      float a0 = att_s[l], a1 = att_s[LL + l], a2 = att_s[2 * LL + l];
      float mm = fmaxf(fmaxf(a0, a1), a2);
      float e0 = __expf(a0 - mm), e1 = __expf(a1 - mm), e2 = __expf(a2 - mm);
      float r = 1.f / (e0 + e1 + e2);
      float ga[6];
      #pragma unroll
      for (int c = 0; c < 6; c++) {
        const float* pb_ = cb + (c * 3) * LL + l;
        float intra = (pb_[0] * e0 + pb_[LL] * e1 + pb_[2 * LL] * e2) * r;
        const float* p0 = curves + (c * 3) * LL + l;   // batch 0
        float pn = p0[0] * wn0 + p0[LL] * wn1 + p0[2 * LL] * wn2 + bnb;
        ga[c] = intra + pn;
      }
      float k0 = 0, k1 = 0, k2 = 0, v0 = 0, v1 = 0, v2 = 0;
      #pragma unroll
      for (int c = 0; c < 6; c++) {
        k0 += wb_r[c] * ga[c];  k1 += wb_r[6 + c] * ga[c];  k2 += wb_r[12 + c] * ga[c];
        v0 += wbv_r[c] * ga[c]; v1 += wbv_r[6 + c] * ga[c]; v2 += wbv_r[12 + c] * ga[c];
      }
      float* o = wkv + l * 6;
      o[0] = k0; o[1] = k1; o[2] = k2; o[3] = v0; o[4] = v1; o[5] = v2;
      km[0] = fmaxf(km[0], fabsf(k0));
      km[1] = fmaxf(km[1], fabsf(k1));
      km[2] = fmaxf(km[2], fabsf(k2));
    }
    #pragma unroll
    for (int j = 0; j < 3; j++) km[j] = wave_reduce_max(km[j]);
    if (lane == 0) { for (int j = 0; j < 3; j++) sred[wid * 3 + j] = km[j]; }
    __syncthreads();
    if (tid == 0) {
      for (int j = 0; j < 3; j++)
        ws[KMAX_OFF + b * 3 + j] =
          fmaxf(fmaxf(sred[j], sred[3 + j]), fmaxf(sred[6 + j], sred[9 + j]));
    }
  }
}

// ---------------------------------------------------------------- main ----
// 512 blocks x 256 thr. Block covers 128 rows. Lane: seg = tid&15 (L-slice of
// 128 keys), grp = (tid>>4)&3. Thread: 8 rows x 128 keys. Segments staggered
// by one float4 (193) -> 16 distinct addrs, 2-way bank alias (free).
__global__ __launch_bounds__(256)
void attn_kernel(const float* __restrict__ x,  const float* __restrict__ Wc,
                 const float* __restrict__ Wd, const float* __restrict__ lng,
                 const float* __restrict__ lnb,
                 float* __restrict__ ws, float* __restrict__ yout)
{
  __shared__ float4 kvs[16 * 193];   // 49408 B
  __shared__ float  cp[48];
  const int tid = threadIdx.x;
  const int blk = blockIdx.x;            // 0..511
  const int seg = tid & 15;
  const int grp = (tid >> 4) & 3;
  const int wv  = tid >> 6;
  const int rbase = blk * 128;           // first row of block
  const int b   = rbase >> 15;
  const int n0  = (rbase + wv * 32 + grp * 8) & (N_PTS - 1);  // first of 8 rows

  const float4* src = (const float4*)(ws + KV_OFF + b * (LL * 6));
  for (int i = tid; i < 3072; i += 256) {
    int s = i / 192;          // 192 float4 per segment
    int t = i - s * 192;
    kvs[s * 193 + t] = src[i];
  }
  __syncthreads();

  // q for 8 consecutive rows (redundant across the 16 segs of a grp - cached)
  const float* xb = x + (size_t)b * 6 * N_PTS + n0;
  float q0[8], q1[8], q2[8], Mp[8], d[8], p0[8], p1[8], p2[8];
  #pragma unroll
  for (int r = 0; r < 8; r++) { q0[r] = q1[r] = q2[r] = 0.f; d[r] = p0[r] = p1[r] = p2[r] = 0.f; }
  #pragma unroll
  for (int c = 0; c < 6; c++) {
    float4 xa = *(const float4*)(xb + c * N_PTS);
    float4 xc = *(const float4*)(xb + c * N_PTS + 4);
    float wc0 = Wc[c], wc1 = Wc[6 + c], wc2 = Wc[12 + c];
    float xv[8] = {xa.x, xa.y, xa.z, xa.w, xc.x, xc.y, xc.z, xc.w};
    #pragma unroll
    for (int r = 0; r < 8; r++) {
      q0[r] = fmaf(xv[r], wc0, q0[r]);
      q1[r] = fmaf(xv[r], wc1, q1[r]);
      q2[r] = fmaf(xv[r], wc2, q2[r]);
    }
  }
  const float KS = 1.4426950408889634f * 0.57735026918962576f;  // log2e / sqrt(3)
  const float* kmx = ws + KMAX_OFF + b * 3;
  float km0 = kmx[0], km1 = kmx[1], km2 = kmx[2];
  #pragma unroll
  for (int r = 0; r < 8; r++) {
    q0[r] *= KS; q1[r] *= KS; q2[r] *= KS;
    Mp[r] = fabsf(q0[r]) * km0 + fabsf(q1[r]) * km1 + fabsf(q2[r]) * km2;
  }

  // single-pass softmax-weighted sums over this seg's 128 keys x 8 rows
  const float4* kp = &kvs[seg * 193];
  #pragma unroll 2
  for (int j = 0; j < 64; j++) {
    float4 A = kp[3 * j], B = kp[3 * j + 1], C = kp[3 * j + 2];
    #pragma unroll
    for (int r = 0; r < 8; r++) {
      float sa = fmaf(q0[r], A.x, fmaf(q1[r], A.y, fmaf(q2[r], A.z, -Mp[r])));
      float ea = __builtin_amdgcn_exp2f(sa);
      d[r] += ea; p0[r] = fmaf(ea, A.w, p0[r]); p1[r] = fmaf(ea, B.x, p1[r]); p2[r] = fmaf(ea, B.y, p2[r]);
      float sb = fmaf(q0[r], B.z, fmaf(q1[r], B.w, fmaf(q2[r], C.x, -Mp[r])));
      float eb = __builtin_amdgcn_exp2f(sb);
      d[r] += eb; p0[r] = fmaf(eb, C.y, p0[r]); p1[r] = fmaf(eb, C.z, p1[r]); p2[r] = fmaf(eb, C.w, p2[r]);
    }
  }

  // butterfly-combine across the 16 segments (Mp is seg-independent)
  #pragma unroll
  for (int m = 1; m <= 8; m <<= 1) {
    #pragma unroll
    for (int r = 0; r < 8; r++) {
      d[r]  += __shfl_xor(d[r],  m, 64);
      p0[r] += __shfl_xor(p0[r], m, 64);
      p1[r] += __shfl_xor(p1[r], m, 64);
      p2[r] += __shfl_xor(p2[r], m, 64);
    }
  }

  // lane seg (<8) takes row n0+seg
  float dd = 0, w0 = 0, w1 = 0, w2 = 0, a0 = 0, a1 = 0, a2 = 0;
  #pragma unroll
  for (int r = 0; r < 8; r++) {
    if (seg == r) { dd = d[r]; w0 = p0[r]; w1 = p1[r]; w2 = p2[r];
                    a0 = q0[r]; a1 = q1[r]; a2 = q2[r]; }
  }
  const bool act = (seg < 8);

  float v12[12];
  #pragma unroll
  for (int j = 0; j < 12; j++) v12[j] = 0.f;

  if (act) {
    const float* ki = ws + KI_OFF + b * 9;
    const float* vi = ws + VI_OFF + b * 9;
    // feature_inter (3 keys, exact softmax)
    float sk0 = a0 * ki[0] + a1 * ki[3] + a2 * ki[6];
    float sk1 = a0 * ki[1] + a1 * ki[4] + a2 * ki[7];
    float sk2 = a0 * ki[2] + a1 * ki[5] + a2 * ki[8];
    float mm  = fmaxf(fmaxf(sk0, sk1), sk2);
    float e0 = __builtin_amdgcn_exp2f(sk0 - mm);
    float e1 = __builtin_amdgcn_exp2f(sk1 - mm);
    float e2 = __builtin_amdgcn_exp2f(sk2 - mm);
    float rs = 1.f / (e0 + e1 + e2);
    float fi0 = (e0 * vi[0] + e1 * vi[3] + e2 * vi[6]) * rs;
    float fi1 = (e0 * vi[1] + e1 * vi[4] + e2 * vi[7]) * rs;
    float fi2 = (e0 * vi[2] + e1 * vi[5] + e2 * vi[8]) * rs;
    float rinv = 1.f / dd;
    float cf[6] = { fi0, fi1, fi2, w0 * rinv, w1 * rinv, w2 * rinv };

    float mu = (cf[0] + cf[1] + cf[2] + cf[3] + cf[4] + cf[5]) * (1.f / 6.f);
    float var = 0.f;
    #pragma unroll
    for (int i = 0; i < 6; i++) { float t = cf[i] - mu; var += t * t; }
    var *= (1.f / 6.f);
    float rn = rsqrtf(var + 1e-5f);
    float cfn[6];
    #pragma unroll
    for (int i = 0; i < 6; i++) cfn[i] = (cf[i] - mu) * rn * lng[i] + lnb[i];

    const int n = n0 + seg;
    #pragma unroll
    for (int o = 0; o < 6; o++) {
      float s = 0.f;
      #pragma unroll
      for (int c = 0; c < 6; c++) s += Wd[o * 6 + c] * cfn[c];
      yout[(size_t)b * (6 * N_PTS) + o * N_PTS + n] = s;
      v12[o] = s; v12[6 + o] = s * s;
    }
  }

  // deterministic BN partials (per block)
  #pragma unroll
  for (int j = 0; j < 12; j++) v12[j] = wave_reduce_sum(v12[j]);
  const int lane = tid & 63, wid = tid >> 6;
  if (lane == 0) { for (int j = 0; j < 12; j++) cp[wid * 12 + j] = v12[j]; }
  __syncthreads();
  if (tid == 0) {
    float* part = ws + PART_OFF + blk * 12;
    for (int j = 0; j < 12; j++)
      part[j] = cp[j] + cp[12 + j] + cp[24 + j] + cp[36 + j];
  }
}

// ------------------------------------------------------------- bn stats ---
__global__ __launch_bounds__(256)
void bnstats_kernel(const float* __restrict__ bng, const float* __restrict__ bnbt,
                    float* __restrict__ ws)
{
  __shared__ float cp[48];
  const int tid = threadIdx.x;
  const float* part = ws + PART_OFF;
  float v[12];
  #pragma unroll
  for (int j = 0; j < 12; j++)
    v[j] = part[tid * 12 + j] + part[(tid + 256) * 12 + j];
  #pragma unroll
  for (int j = 0; j < 12; j++) v[j] = wave_reduce_sum(v[j]);
  const int lane = tid & 63, wid = tid >> 6;
  if (lane == 0) { for (int j = 0; j < 12; j++) cp[wid * 12 + j] = v[j]; }
  __syncthreads();
  if (tid == 0) {
    const float inv = 1.f / 65536.f;   // B * N
    for (int o = 0; o < 6; o++) {
      float s1 = cp[o] + cp[12 + o] + cp[24 + o] + cp[36 + o];
      float s2 = cp[6 + o] + cp[18 + o] + cp[30 + o] + cp[42 + o];
      float mean = s1 * inv;
      float varr = s2 * inv - mean * mean;
      float sc = bng[o] * rsqrtf(varr + 1e-5f);
      ws[BNS_OFF + o] = sc;
      ws[BNB_OFF + o] = bnbt[o] - mean * sc;
    }
  }
}

// ------------------------------------------------------------- finalize ---
__global__ __launch_bounds__(256)
void final_kernel(const float* __restrict__ x, const float* __restrict__ ws,
                  float* __restrict__ out)
{
  const int i = blockIdx.x * 256 + threadIdx.x;   // 393216 total
  const int ch = (i >> 15) % 6;
  float v = out[i] * ws[BNS_OFF + ch] + ws[BNB_OFF + ch] + x[i];
  out[i] = v >= 0.f ? v : 0.2f * v;
}

// ---------------------------------------------------------------- launch --
extern "C" void kernel_launch(void* const* d_in, const int* in_sizes, int n_in,
                              void* d_out, int out_size, void* d_ws, size_t ws_size,
                              hipStream_t stream)
{
  const float* x      = (const float*)d_in[0];
  const float* curves = (const float*)d_in[1];
  const float* Wa     = (const float*)d_in[2];
  const float* Wav    = (const float*)d_in[3];
  const float* Wb     = (const float*)d_in[4];
  const float* Wbv    = (const float*)d_in[5];
  const float* Wc     = (const float*)d_in[6];
  const float* Wd     = (const float*)d_in[7];
  const float* bng    = (const float*)d_in[8];
  const float* bnbt   = (const float*)d_in[9];
  const float* Watt   = (const float*)d_in[10];
  const float* lng    = (const float*)d_in[11];
  const float* lnbt   = (const float*)d_in[12];
  const float* Wpl    = (const float*)d_in[13];
  const float* bpl    = (const float*)d_in[14];
  const float* Wpn    = (const float*)d_in[15];
  const float* bpn    = (const float*)d_in[16];
  float* out = (float*)d_out;
  float* ws  = (float*)d_ws;

  prep_kernel<<<2, 256, 0, stream>>>(curves, Wa, Wav, Wb, Wbv, Watt,
                                     Wpl, bpl, Wpn, bpn, ws);
  attn_kernel<<<512, 256, 0, stream>>>(x, Wc, Wd, lng, lnbt, ws, out);
  bnstats_kernel<<<1, 256, 0, stream>>>(bng, bnbt, ws);
  final_kernel<<<1536, 256, 0, stream>>>(x, ws, out);
}

// Round 5
// 66.951 us; speedup vs baseline: 1.1792x; 1.0037x over previous
//
#include <hip/hip_runtime.h>
#include <math.h>

#define N_PTS 32768
#define LL    2048

// d_ws float offsets
#define KVH_OFF   0          // [2][1024 pairs][6 dwords] f16-pair kv table
#define KI_OFF    12288      // [2][3][3]  k_inter[m][k]
#define VI_OFF    12306      // [2][3][3]  v_inter[k][m]
#define KMAX_OFF  12324      // [2][3]     max_l |k_m|
#define PART_OFF  12330      // [512][12]  BN partials (sum, sumsq)
#define BNS_OFF   18474      // [6] scale
#define BNB_OFF   18480      // [6] shift

typedef __fp16 h2 __attribute__((ext_vector_type(2)));

__device__ __forceinline__ h2 as_h2(unsigned u){
  union { unsigned u; h2 h; } x; x.u = u; return x.h;
}
__device__ __forceinline__ unsigned h2_bits(h2 h){
  union { h2 h; unsigned u; } x; x.h = h; return x.u;
}
__device__ __forceinline__ float wave_reduce_sum(float v){
  #pragma unroll
  for (int off = 32; off; off >>= 1) v += __shfl_xor(v, off, 64);
  return v;
}
__device__ __forceinline__ float wave_reduce_max(float v){
  #pragma unroll
  for (int off = 32; off; off >>= 1) v = fmaxf(v, __shfl_xor(v, off, 64));
  return v;
}

#define PREP_NT 512
#define PREP_NW 8

// ---------------------------------------------------------------- prep ----
__global__ __launch_bounds__(PREP_NT)
void prep_kernel(const float* __restrict__ curves,
                 const float* __restrict__ Wa,  const float* __restrict__ Wav,
                 const float* __restrict__ Wb,  const float* __restrict__ Wbv,
                 const float* __restrict__ Watt,
                 const float* __restrict__ Wpl, const float* __restrict__ bpl,
                 const float* __restrict__ Wpn, const float* __restrict__ bpn,
                 float* __restrict__ ws)
{
  const int b    = blockIdx.x;
  const int tid  = threadIdx.x;
  const int lane = tid & 63, wid = tid >> 6;

  __shared__ float att_s[3 * LL];     // 24 KB
  __shared__ float sred[PREP_NW * 36];
  __shared__ float m_nc[3], s_nc[3];

  float watt[6];
  #pragma unroll
  for (int c = 0; c < 6; c++) watt[c] = Watt[c];

  const float* cb = curves + b * 6 * 3 * LL;

  // S1: att[nc][l] = sum_c curves[b,c,nc,l] * Watt[c]
  for (int idx = tid; idx < 3 * LL; idx += PREP_NT) {
    int nc = idx >> 11, l = idx & (LL - 1);
    float s = 0.f;
    #pragma unroll
    for (int c = 0; c < 6; c++) s += cb[(c * 3 + nc) * LL + l] * watt[c];
    att_s[idx] = s;
  }
  __syncthreads();

  // S2a: max over L per nc
  {
    float pm[3] = {-1e30f, -1e30f, -1e30f};
    for (int l = tid; l < LL; l += PREP_NT) {
      #pragma unroll
      for (int nc = 0; nc < 3; nc++) pm[nc] = fmaxf(pm[nc], att_s[nc * LL + l]);
    }
    #pragma unroll
    for (int j = 0; j < 3; j++) pm[j] = wave_reduce_max(pm[j]);
    if (lane == 0) { for (int j = 0; j < 3; j++) sred[wid * 3 + j] = pm[j]; }
    __syncthreads();
    if (tid == 0) {
      for (int j = 0; j < 3; j++) {
        float m = sred[j];
        for (int w = 1; w < PREP_NW; w++) m = fmaxf(m, sred[w * 3 + j]);
        m_nc[j] = m;
      }
    }
    __syncthreads();
  }
  // S2b: sum of exp over L per nc
  {
    float ps[3] = {0.f, 0.f, 0.f};
    for (int l = tid; l < LL; l += PREP_NT) {
      #pragma unroll
      for (int nc = 0; nc < 3; nc++) ps[nc] += __expf(att_s[nc * LL + l] - m_nc[nc]);
    }
    #pragma unroll
    for (int j = 0; j < 3; j++) ps[j] = wave_reduce_sum(ps[j]);
    if (lane == 0) { for (int j = 0; j < 3; j++) sred[wid * 3 + j] = ps[j]; }
    __syncthreads();
    if (tid == 0) {
      for (int j = 0; j < 3; j++) {
        float s = 0.f;
        for (int w = 0; w < PREP_NW; w++) s += sred[w * 3 + j];
        s_nc[j] = s;
      }
    }
    __syncthreads();
  }

  // S3: partials for curver_inter (weighted by exp) and pbar (curves[0] mean)
  {
    float pv[36];
    #pragma unroll
    for (int j = 0; j < 36; j++) pv[j] = 0.f;
    for (int l = tid; l < LL; l += PREP_NT) {
      #pragma unroll
      for (int nc = 0; nc < 3; nc++) {
        float e = __expf(att_s[nc * LL + l] - m_nc[nc]);
        #pragma unroll
        for (int c = 0; c < 6; c++) {
          pv[c * 3 + nc]      += cb[(c * 3 + nc) * LL + l] * e;
          pv[18 + c * 3 + nc] += curves[(c * 3 + nc) * LL + l];   // batch 0
        }
      }
    }
    #pragma unroll
    for (int j = 0; j < 36; j++) pv[j] = wave_reduce_sum(pv[j]);
    if (lane == 0) { for (int j = 0; j < 36; j++) sred[wid * 36 + j] = pv[j]; }
    __syncthreads();
    if (tid == 0) {
      float tot[36];
      for (int j = 0; j < 36; j++) {
        float s = 0.f;
        for (int w = 0; w < PREP_NW; w++) s += sred[w * 36 + j];
        tot[j] = s;
      }
      // p_l[c][m] = bpl[m] + sum_k Wpl[m,k] * mean_l(curves0[c,k,l])
      float gi[18];
      for (int c = 0; c < 6; c++) {
        for (int m = 0; m < 3; m++) {
          float pl = bpl[m];
          for (int k = 0; k < 3; k++)
            pl += Wpl[m * 3 + k] * (tot[18 + c * 3 + k] * (1.f / LL));
          gi[c * 3 + m] = tot[c * 3 + m] / s_nc[m] + pl;
        }
      }
      for (int m = 0; m < 3; m++)
        for (int k = 0; k < 3; k++) {
          float ki = 0.f, vi = 0.f;
          for (int c = 0; c < 6; c++) {
            ki += Wa [m * 6 + c] * gi[c * 3 + k];
            vi += Wav[m * 6 + c] * gi[c * 3 + k];
          }
          ws[KI_OFF + b * 9 + m * 3 + k] = ki;
          ws[VI_OFF + b * 9 + k * 3 + m] = vi;   // [k][m]
        }
    }
    __syncthreads();
  }

  // S5: per key-pair: softmax over nc, ga, k_intra/v_intra (f16 pairs), |k| max
  {
    float wb_r[18], wbv_r[18];
    #pragma unroll
    for (int i = 0; i < 18; i++) { wb_r[i] = Wb[i]; wbv_r[i] = Wbv[i]; }
    float wn0 = (Wpn[0] + Wpn[3] + Wpn[6]) * (1.f / 3.f);
    float wn1 = (Wpn[1] + Wpn[4] + Wpn[7]) * (1.f / 3.f);
    float wn2 = (Wpn[2] + Wpn[5] + Wpn[8]) * (1.f / 3.f);
    float bnb = (bpn[0] + bpn[1] + bpn[2]) * (1.f / 3.f);
    float km[3] = {0.f, 0.f, 0.f};
    unsigned* wkv = (unsigned*)(ws + KVH_OFF) + b * 6144;

    for (int pp = tid; pp < 1024; pp += PREP_NT) {
      const int l = 2 * pp;
      float2 A0 = *(const float2*)&att_s[l];
      float2 A1 = *(const float2*)&att_s[LL + l];
      float2 A2 = *(const float2*)&att_s[2 * LL + l];
      float kk[2][3], vv[2][3];
      #pragma unroll
      for (int e = 0; e < 2; e++) {
        float a0 = e ? A0.y : A0.x, a1 = e ? A1.y : A1.x, a2 = e ? A2.y : A2.x;
        float mm = fmaxf(fmaxf(a0, a1), a2);
        float e0 = __expf(a0 - mm), e1 = __expf(a1 - mm), e2 = __expf(a2 - mm);
        float r = 1.f / (e0 + e1 + e2);
        float ga[6];
        #pragma unroll
        for (int c = 0; c < 6; c++) {
          const float* pb_ = cb + (c * 3) * LL + l + e;
          float intra = (pb_[0] * e0 + pb_[LL] * e1 + pb_[2 * LL] * e2) * r;
          const float* p0 = curves + (c * 3) * LL + l + e;   // batch 0
          float pn = p0[0] * wn0 + p0[LL] * wn1 + p0[2 * LL] * wn2 + bnb;
          ga[c] = intra + pn;
        }
        float k0 = 0, k1 = 0, k2 = 0, v0 = 0, v1 = 0, v2 = 0;
        #pragma unroll
        for (int c = 0; c < 6; c++) {
          k0 += wb_r[c] * ga[c];  k1 += wb_r[6 + c] * ga[c];  k2 += wb_r[12 + c] * ga[c];
          v0 += wbv_r[c] * ga[c]; v1 += wbv_r[6 + c] * ga[c]; v2 += wbv_r[12 + c] * ga[c];
        }
        kk[e][0] = k0; kk[e][1] = k1; kk[e][2] = k2;
        vv[e][0] = v0; vv[e][1] = v1; vv[e][2] = v2;
        km[0] = fmaxf(km[0], fabsf(k0));
        km[1] = fmaxf(km[1], fabsf(k1));
        km[2] = fmaxf(km[2], fabsf(k2));
      }
      unsigned* o = wkv + pp * 6;
      o[0] = h2_bits(__builtin_amdgcn_cvt_pkrtz(kk[0][0], kk[0][1]));
      o[1] = h2_bits(__builtin_amdgcn_cvt_pkrtz(kk[1][0], kk[1][1]));
      o[2] = h2_bits(__builtin_amdgcn_cvt_pkrtz(kk[0][2], kk[1][2]));
      o[3] = h2_bits(__builtin_amdgcn_cvt_pkrtz(vv[0][0], vv[1][0]));
      o[4] = h2_bits(__builtin_amdgcn_cvt_pkrtz(vv[0][1], vv[1][1]));
      o[5] = h2_bits(__builtin_amdgcn_cvt_pkrtz(vv[0][2], vv[1][2]));
    }
    #pragma unroll
    for (int j = 0; j < 3; j++) km[j] = wave_reduce_max(km[j]);
    if (lane == 0) { for (int j = 0; j < 3; j++) sred[wid * 3 + j] = km[j]; }
    __syncthreads();
    if (tid == 0) {
      for (int j = 0; j < 3; j++) {
        float m = sred[j];
        for (int w = 1; w < PREP_NW; w++) m = fmaxf(m, sred[w * 3 + j]);
        ws[KMAX_OFF + b * 3 + j] = m;
      }
    }
  }
}

// ---------------------------------------------------------------- main ----
// 512 blocks x 512 thr. Block = 128 rows, full L staged as f16 pairs (25 KB).
// wv = tid>>6: h = wv>>2 (L-half), rg4 = wv&3. lane: seg = lane&15 (64 keys),
// grp = (lane>>4)&3. Thread: 8 rows x 64 keys, f16 dot2 pipeline.
// Halves combined via LDS cross-buffer; tail on threads 0-127.
__global__ __launch_bounds__(512)
void attn_kernel(const float* __restrict__ x,  const float* __restrict__ Wc,
                 const float* __restrict__ Wd, const float* __restrict__ lng,
                 const float* __restrict__ lnb,
                 float* __restrict__ ws, float* __restrict__ yout)
{
  __shared__ float4 kvs4[32 * 49];    // 25088 B (48 used per 49-slot, stagger pad)
  __shared__ float4 cross4[256];      // [h][r128] {d,p0,p1,p2}
  __shared__ float  cp[PREP_NW * 12];
  const int tid  = threadIdx.x;
  const int blk  = blockIdx.x;            // 0..511
  const int lane = tid & 63, wv = tid >> 6;
  const int seg  = lane & 15;
  const int grp  = (lane >> 4) & 3;
  const int h    = wv >> 2;
  const int rg4  = wv & 3;
  const int rbase = blk * 128;
  const int b    = rbase >> 15;
  const int nb   = rbase & (N_PTS - 1);   // block-first row within batch

  // stage f16 pair table: 1536 float4, slot s covers pairs [32s, 32s+32)
  const float4* src = (const float4*)(ws + KVH_OFF) + b * 1536;
  for (int i = tid; i < 1536; i += 512) {
    int s = i / 48, t = i - s * 48;
    kvs4[s * 49 + t] = src[i];
  }
  __syncthreads();

  // q for 8 rows
  const int n0 = nb + rg4 * 32 + grp * 8;
  const float* xb = x + (size_t)b * 6 * N_PTS + n0;
  float q0[8], q1[8], q2[8];
  #pragma unroll
  for (int r = 0; r < 8; r++) q0[r] = q1[r] = q2[r] = 0.f;
  #pragma unroll
  for (int c = 0; c < 6; c++) {
    float4 xa = *(const float4*)(xb + c * N_PTS);
    float4 xc = *(const float4*)(xb + c * N_PTS + 4);
    float wc0 = Wc[c], wc1 = Wc[6 + c], wc2 = Wc[12 + c];
    float xv[8] = {xa.x, xa.y, xa.z, xa.w, xc.x, xc.y, xc.z, xc.w};
    #pragma unroll
    for (int r = 0; r < 8; r++) {
      q0[r] = fmaf(xv[r], wc0, q0[r]);
      q1[r] = fmaf(xv[r], wc1, q1[r]);
      q2[r] = fmaf(xv[r], wc2, q2[r]);
    }
  }
  const float KS = 1.4426950408889634f * 0.57735026918962576f;  // log2e/sqrt(3)
  const float* kmx = ws + KMAX_OFF + b * 3;
  float km0 = kmx[0], km1 = kmx[1], km2 = kmx[2];
  h2 q01h[8], q2A[8], q2B[8];
  float mMp[8];
  #pragma unroll
  for (int r = 0; r < 8; r++) {
    q0[r] *= KS; q1[r] *= KS; q2[r] *= KS;
    q01h[r] = __builtin_amdgcn_cvt_pkrtz(q0[r], q1[r]);
    q2A[r]  = __builtin_amdgcn_cvt_pkrtz(q2[r], 0.f);
    q2B[r]  = __builtin_amdgcn_cvt_pkrtz(0.f, q2[r]);
    mMp[r]  = -(fabsf(q0[r]) * km0 + fabsf(q1[r]) * km1 + fabsf(q2[r]) * km2);
  }

  const h2 one2 = {(__fp16)1.f, (__fp16)1.f};
  float d[8], p0[8], p1[8], p2[8];
  #pragma unroll
  for (int r = 0; r < 8; r++) d[r] = p0[r] = p1[r] = p2[r] = 0.f;

  // 64 keys = 16 iters x 4 keys (2 pair-records = 3 float4)
  const float4* base = &kvs4[(h * 16 + seg) * 49];
  #pragma unroll 2
  for (int j = 0; j < 16; j++) {
    float4 F0 = base[3 * j], F1 = base[3 * j + 1], F2 = base[3 * j + 2];
    union { float4 f; unsigned u[4]; } U0, U1, U2;
    U0.f = F0; U1.f = F1; U2.f = F2;
    h2 k01a = as_h2(U0.u[0]), k01b = as_h2(U0.u[1]), k2ab = as_h2(U0.u[2]);
    h2 v0ab = as_h2(U0.u[3]), v1ab = as_h2(U1.u[0]), v2ab = as_h2(U1.u[1]);
    h2 k01c = as_h2(U1.u[2]), k01d = as_h2(U1.u[3]), k2cd = as_h2(U2.u[0]);
    h2 v0cd = as_h2(U2.u[1]), v1cd = as_h2(U2.u[2]), v2cd = as_h2(U2.u[3]);
    #pragma unroll
    for (int r = 0; r < 8; r++) {
      float sa = __builtin_amdgcn_fdot2(q01h[r], k01a,
                   __builtin_amdgcn_fdot2(q2A[r], k2ab, mMp[r], false), false);
      float sb = __builtin_amdgcn_fdot2(q01h[r], k01b,
                   __builtin_amdgcn_fdot2(q2B[r], k2ab, mMp[r], false), false);
      float sc = __builtin_amdgcn_fdot2(q01h[r], k01c,
                   __builtin_amdgcn_fdot2(q2A[r], k2cd, mMp[r], false), false);
      float sd = __builtin_amdgcn_fdot2(q01h[r], k01d,
                   __builtin_amdgcn_fdot2(q2B[r], k2cd, mMp[r], false), false);
      float ea = __builtin_amdgcn_exp2f(sa);
      float eb = __builtin_amdgcn_exp2f(sb);
      float ec = __builtin_amdgcn_exp2f(sc);
      float ed = __builtin_amdgcn_exp2f(sd);
      h2 eab = __builtin_amdgcn_cvt_pkrtz(ea, eb);
      h2 ecd = __builtin_amdgcn_cvt_pkrtz(ec, ed);
      d[r]  = __builtin_amdgcn_fdot2(eab, one2,
                __builtin_amdgcn_fdot2(ecd, one2, d[r],  false), false);
      p0[r] = __builtin_amdgcn_fdot2(eab, v0ab,
                __builtin_amdgcn_fdot2(ecd, v0cd, p0[r], false), false);
      p1[r] = __builtin_amdgcn_fdot2(eab, v1ab,
                __builtin_amdgcn_fdot2(ecd, v1cd, p1[r], false), false);
      p2[r] = __builtin_amdgcn_fdot2(eab, v2ab,
                __builtin_amdgcn_fdot2(ecd, v2cd, p2[r], false), false);
    }
  }

  // butterfly-combine across the 16 segments (Mp is seg-independent)
  #pragma unroll
  for (int m = 1; m <= 8; m <<= 1) {
    #pragma unroll
    for (int r = 0; r < 8; r++) {
      d[r]  += __shfl_xor(d[r],  m, 64);
      p0[r] += __shfl_xor(p0[r], m, 64);
      p1[r] += __shfl_xor(p1[r], m, 64);
      p2[r] += __shfl_xor(p2[r], m, 64);
    }
  }

  // lane seg<8 publishes row (rg4*32 + grp*8 + seg) for its half h
  if (seg < 8) {
    float dd = 0, w0 = 0, w1 = 0, w2 = 0;
    #pragma unroll
    for (int r = 0; r < 8; r++)
      if (seg == r) { dd = d[r]; w0 = p0[r]; w1 = p1[r]; w2 = p2[r]; }
    cross4[h * 128 + rg4 * 32 + grp * 8 + seg] = make_float4(dd, w0, w1, w2);
  }
  __syncthreads();

  float v12[12];
  #pragma unroll
  for (int j = 0; j < 12; j++) v12[j] = 0.f;

  if (tid < 128) {
    const int r = tid;
    const int n = nb + r;
    float4 c0 = cross4[r], c1 = cross4[128 + r];
    float dd = c0.x + c1.x, w0 = c0.y + c1.y, w1 = c0.z + c1.z, w2 = c0.w + c1.w;

    // recompute q (scaled)
    const float* xr = x + (size_t)b * 6 * N_PTS + n;
    float a0 = 0, a1 = 0, a2 = 0;
    #pragma unroll
    for (int c = 0; c < 6; c++) {
      float xv = xr[c * N_PTS];
      a0 = fmaf(xv, Wc[c], a0); a1 = fmaf(xv, Wc[6 + c], a1); a2 = fmaf(xv, Wc[12 + c], a2);
    }
    a0 *= KS; a1 *= KS; a2 *= KS;

    const float* ki = ws + KI_OFF + b * 9;
    const float* vi = ws + VI_OFF + b * 9;
    float sk0 = a0 * ki[0] + a1 * ki[3] + a2 * ki[6];
    float sk1 = a0 * ki[1] + a1 * ki[4] + a2 * ki[7];
    float sk2 = a0 * ki[2] + a1 * ki[5] + a2 * ki[8];
    float mm  = fmaxf(fmaxf(sk0, sk1), sk2);
    float e0 = __builtin_amdgcn_exp2f(sk0 - mm);
    float e1 = __builtin_amdgcn_exp2f(sk1 - mm);
    float e2 = __builtin_amdgcn_exp2f(sk2 - mm);
    float rs = 1.f / (e0 + e1 + e2);
    float fi0 = (e0 * vi[0] + e1 * vi[3] + e2 * vi[6]) * rs;
    float fi1 = (e0 * vi[1] + e1 * vi[4] + e2 * vi[7]) * rs;
    float fi2 = (e0 * vi[2] + e1 * vi[5] + e2 * vi[8]) * rs;
    float rinv = 1.f / dd;
    float cf[6] = { fi0, fi1, fi2, w0 * rinv, w1 * rinv, w2 * rinv };

    float mu = (cf[0] + cf[1] + cf[2] + cf[3] + cf[4] + cf[5]) * (1.f / 6.f);
    float var = 0.f;
    #pragma unroll
    for (int i = 0; i < 6; i++) { float t = cf[i] - mu; var += t * t; }
    var *= (1.f / 6.f);
    float rn = rsqrtf(var + 1e-5f);
    float cfn[6];
    #pragma unroll
    for (int i = 0; i < 6; i++) cfn[i] = (cf[i] - mu) * rn * lng[i] + lnb[i];

    #pragma unroll
    for (int o = 0; o < 6; o++) {
      float s = 0.f;
      #pragma unroll
      for (int c = 0; c < 6; c++) s += Wd[o * 6 + c] * cfn[c];
      yout[(size_t)b * (6 * N_PTS) + o * N_PTS + n] = s;
      v12[o] = s; v12[6 + o] = s * s;
    }
  }

  // deterministic BN partials (per block)
  #pragma unroll
  for (int j = 0; j < 12; j++) v12[j] = wave_reduce_sum(v12[j]);
  if (lane == 0) { for (int j = 0; j < 12; j++) cp[wv * 12 + j] = v12[j]; }
  __syncthreads();
  if (tid == 0) {
    float* part = ws + PART_OFF + blk * 12;
    for (int j = 0; j < 12; j++) {
      float s = 0.f;
      for (int w = 0; w < 8; w++) s += cp[w * 12 + j];
      part[j] = s;
    }
  }
}

// ------------------------------------------------------------- bn stats ---
__global__ __launch_bounds__(256)
void bnstats_kernel(const float* __restrict__ bng, const float* __restrict__ bnbt,
                    float* __restrict__ ws)
{
  __shared__ float cp[48];
  const int tid = threadIdx.x;
  const float* part = ws + PART_OFF;
  float v[12];
  #pragma unroll
  for (int j = 0; j < 12; j++)
    v[j] = part[tid * 12 + j] + part[(tid + 256) * 12 + j];
  #pragma unroll
  for (int j = 0; j < 12; j++) v[j] = wave_reduce_sum(v[j]);
  const int lane = tid & 63, wid = tid >> 6;
  if (lane == 0) { for (int j = 0; j < 12; j++) cp[wid * 12 + j] = v[j]; }
  __syncthreads();
  if (tid == 0) {
    const float inv = 1.f / 65536.f;   // B * N
    for (int o = 0; o < 6; o++) {
      float s1 = cp[o] + cp[12 + o] + cp[24 + o] + cp[36 + o];
      float s2 = cp[6 + o] + cp[18 + o] + cp[30 + o] + cp[42 + o];
      float mean = s1 * inv;
      float varr = s2 * inv - mean * mean;
      float sc = bng[o] * rsqrtf(varr + 1e-5f);
      ws[BNS_OFF + o] = sc;
      ws[BNB_OFF + o] = bnbt[o] - mean * sc;
    }
  }
}

// ------------------------------------------------------------- finalize ---
__global__ __launch_bounds__(256)
void final_kernel(const float* __restrict__ x, const float* __restrict__ ws,
                  float* __restrict__ out)
{
  const int i = blockIdx.x * 256 + threadIdx.x;   // 393216 total
  const int ch = (i >> 15) % 6;
  float v = out[i] * ws[BNS_OFF + ch] + ws[BNB_OFF + ch] + x[i];
  out[i] = v >= 0.f ? v : 0.2f * v;
}

// ---------------------------------------------------------------- launch --
extern "C" void kernel_launch(void* const* d_in, const int* in_sizes, int n_in,
                              void* d_out, int out_size, void* d_ws, size_t ws_size,
                              hipStream_t stream)
{
  const float* x      = (const float*)d_in[0];
  const float* curves = (const float*)d_in[1];
  const float* Wa     = (const float*)d_in[2];
  const float* Wav    = (const float*)d_in[3];
  const float* Wb     = (const float*)d_in[4];
  const float* Wbv    = (const float*)d_in[5];
  const float* Wc     = (const float*)d_in[6];
  const float* Wd     = (const float*)d_in[7];
  const float* bng    = (const float*)d_in[8];
  const float* bnbt   = (const float*)d_in[9];
  const float* Watt   = (const float*)d_in[10];
  const float* lng    = (const float*)d_in[11];
  const float* lnbt   = (const float*)d_in[12];
  const float* Wpl    = (const float*)d_in[13];
  const float* bpl    = (const float*)d_in[14];
  const float* Wpn    = (const float*)d_in[15];
  const float* bpn    = (const float*)d_in[16];
  float* out = (float*)d_out;
  float* ws  = (float*)d_ws;

  prep_kernel<<<2, PREP_NT, 0, stream>>>(curves, Wa, Wav, Wb, Wbv, Watt,
                                         Wpl, bpl, Wpn, bpn, ws);
  attn_kernel<<<512, 512, 0, stream>>>(x, Wc, Wd, lng, lnbt, ws, out);
  bnstats_kernel<<<1, 256, 0, stream>>>(bng, bnbt, ws);
  final_kernel<<<1536, 256, 0, stream>>>(x, ws, out);
}

// Round 6
// 58.265 us; speedup vs baseline: 1.3550x; 1.1491x over previous
//
#include <hip/hip_runtime.h>
#include <math.h>

#define N_PTS 32768
#define LL    2048

// d_ws float offsets
#define KVH_OFF   0          // [2][1024 pairs][6 dwords] f16-pair kv table
#define ATT_OFF   12288      // [2][3][2048] att scores
#define KI_OFF    24576      // [2][3][3]  k_inter[m][k]
#define VI_OFF    24594      // [2][3][3]  v_inter[k][m]
#define KMAX_OFF  24612      // [2][3]     max_l |k_m| (uint-bits atomic max)
#define MS_OFF    24618      // [6][2]     {m, s} per (b*3+nc)
#define W_OFF     24630      // [6][6]     W[b*3+nc][c] exp-weighted sums
#define CS_OFF    24666      // [3][6]     colsum[nc][c] batch0
#define PART_OFF  24684      // [512][12]  BN partials
#define BNS_OFF   30828      // [6] scale
#define BNB_OFF   30834      // [6] shift

typedef __fp16 h2 __attribute__((ext_vector_type(2)));

__device__ __forceinline__ h2 as_h2(unsigned u){
  union { unsigned u; h2 h; } x; x.u = u; return x.h;
}
__device__ __forceinline__ unsigned h2_bits(h2 h){
  union { h2 h; unsigned u; } x; x.h = h; return x.u;
}
__device__ __forceinline__ float wave_reduce_sum(float v){
  #pragma unroll
  for (int off = 32; off; off >>= 1) v += __shfl_xor(v, off, 64);
  return v;
}
__device__ __forceinline__ float wave_reduce_max(float v){
  #pragma unroll
  for (int off = 32; off; off >>= 1) v = fmaxf(v, __shfl_xor(v, off, 64));
  return v;
}

// --------------------------------------------------------------- prep1 ----
// grid 6 = (b,nc). Computes att row -> ws, global max m, expsum s,
// W[c] = sum_l cb[c,nc,l]*exp(att-m), and (b==0) colsum[c] = sum_l curves0.
__global__ __launch_bounds__(512)
void prep1_kernel(const float* __restrict__ curves,
                  const float* __restrict__ Watt, float* __restrict__ ws)
{
  const int blk = blockIdx.x;          // b*3 + nc
  const int b = blk / 3, nc = blk % 3;
  const int tid = threadIdx.x, lane = tid & 63, wid = tid >> 6;
  __shared__ float sred[8 * 13];
  __shared__ float mshare;

  float watt[6];
  #pragma unroll
  for (int c = 0; c < 6; c++) watt[c] = Watt[c];
  const float* cb = curves + b * 6 * 3 * LL;

  float av[4], cbv[4][6];
  #pragma unroll
  for (int k = 0; k < 4; k++) {
    const int l = tid + k * 512;
    float s = 0.f;
    #pragma unroll
    for (int c = 0; c < 6; c++) {
      float v = cb[(c * 3 + nc) * LL + l];
      cbv[k][c] = v;
      s = fmaf(v, watt[c], s);
    }
    av[k] = s;
    ws[ATT_OFF + blk * LL + l] = s;
  }
  // global max over L
  float pm = fmaxf(fmaxf(av[0], av[1]), fmaxf(av[2], av[3]));
  pm = wave_reduce_max(pm);
  if (lane == 0) sred[wid] = pm;
  __syncthreads();
  if (tid == 0) {
    float m = sred[0];
    for (int w = 1; w < 8; w++) m = fmaxf(m, sred[w]);
    mshare = m;
  }
  __syncthreads();
  const float m = mshare;

  float vals[13];
  #pragma unroll
  for (int j = 0; j < 13; j++) vals[j] = 0.f;
  #pragma unroll
  for (int k = 0; k < 4; k++) {
    float e = __expf(av[k] - m);
    vals[0] += e;
    #pragma unroll
    for (int c = 0; c < 6; c++) {
      vals[1 + c] = fmaf(cbv[k][c], e, vals[1 + c]);
      if (b == 0) vals[7 + c] += cbv[k][c];
    }
  }
  #pragma unroll
  for (int j = 0; j < 13; j++) vals[j] = wave_reduce_sum(vals[j]);
  if (lane == 0) { for (int j = 0; j < 13; j++) sred[wid * 13 + j] = vals[j]; }
  __syncthreads();
  if (tid == 0) {
    float t[13];
    for (int j = 0; j < 13; j++) {
      float s = 0.f;
      for (int w = 0; w < 8; w++) s += sred[w * 13 + j];
      t[j] = s;
    }
    ws[MS_OFF + blk * 2]     = m;
    ws[MS_OFF + blk * 2 + 1] = t[0];
    for (int c = 0; c < 6; c++) ws[W_OFF + blk * 6 + c] = t[1 + c];
    if (b == 0) for (int c = 0; c < 6; c++) ws[CS_OFF + nc * 6 + c] = t[7 + c];
  }
  if (blk == 0 && tid < 6) ((unsigned*)ws)[KMAX_OFF + tid] = 0u;
}

// ------------------------------------------------------------------ kv ----
// grid 16 x 128: one key-PAIR per thread. Local softmax over nc, ga,
// k/v f16 pack, |k|-max via uint atomicMax. Block 0 thread 0 also computes
// k_inter / v_inter (tiny algebra on prep1's sums).
__global__ __launch_bounds__(128)
void kv_kernel(const float* __restrict__ curves,
               const float* __restrict__ Wa,  const float* __restrict__ Wav,
               const float* __restrict__ Wb,  const float* __restrict__ Wbv,
               const float* __restrict__ Wpl, const float* __restrict__ bpl,
               const float* __restrict__ Wpn, const float* __restrict__ bpn,
               float* __restrict__ ws)
{
  const int idx = blockIdx.x * 128 + threadIdx.x;   // 0..2047
  const int b = idx >> 10, pp = idx & 1023, l = pp * 2;
  const float* cb = curves + b * 6 * 3 * LL;

  float2 a[3];
  #pragma unroll
  for (int nc = 0; nc < 3; nc++)
    a[nc] = *(const float2*)&ws[ATT_OFF + (b * 3 + nc) * LL + l];

  float2 cv[6][3], pv[6][3];
  #pragma unroll
  for (int c = 0; c < 6; c++)
    #pragma unroll
    for (int nc = 0; nc < 3; nc++) {
      cv[c][nc] = *(const float2*)&cb[(c * 3 + nc) * LL + l];
      pv[c][nc] = *(const float2*)&curves[(c * 3 + nc) * LL + l];  // batch 0
    }

  float wb_r[18], wbv_r[18];
  #pragma unroll
  for (int i = 0; i < 18; i++) { wb_r[i] = Wb[i]; wbv_r[i] = Wbv[i]; }
  const float wn0 = (Wpn[0] + Wpn[3] + Wpn[6]) * (1.f / 3.f);
  const float wn1 = (Wpn[1] + Wpn[4] + Wpn[7]) * (1.f / 3.f);
  const float wn2 = (Wpn[2] + Wpn[5] + Wpn[8]) * (1.f / 3.f);
  const float bnb = (bpn[0] + bpn[1] + bpn[2]) * (1.f / 3.f);

  float kk[2][3], vv[2][3], km[3] = {0.f, 0.f, 0.f};
  #pragma unroll
  for (int e = 0; e < 2; e++) {
    float a0 = e ? a[0].y : a[0].x;
    float a1 = e ? a[1].y : a[1].x;
    float a2 = e ? a[2].y : a[2].x;
    float mm = fmaxf(fmaxf(a0, a1), a2);
    float e0 = __expf(a0 - mm), e1 = __expf(a1 - mm), e2 = __expf(a2 - mm);
    float r = 1.f / (e0 + e1 + e2);
    float ga[6];
    #pragma unroll
    for (int c = 0; c < 6; c++) {
      float c0 = e ? cv[c][0].y : cv[c][0].x;
      float c1 = e ? cv[c][1].y : cv[c][1].x;
      float c2 = e ? cv[c][2].y : cv[c][2].x;
      float p0 = e ? pv[c][0].y : pv[c][0].x;
      float p1 = e ? pv[c][1].y : pv[c][1].x;
      float p2 = e ? pv[c][2].y : pv[c][2].x;
      float intra = (c0 * e0 + c1 * e1 + c2 * e2) * r;
      float pn = p0 * wn0 + p1 * wn1 + p2 * wn2 + bnb;
      ga[c] = intra + pn;
    }
    float k0 = 0, k1 = 0, k2 = 0, v0 = 0, v1 = 0, v2 = 0;
    #pragma unroll
    for (int c = 0; c < 6; c++) {
      k0 += wb_r[c] * ga[c];  k1 += wb_r[6 + c] * ga[c];  k2 += wb_r[12 + c] * ga[c];
      v0 += wbv_r[c] * ga[c]; v1 += wbv_r[6 + c] * ga[c]; v2 += wbv_r[12 + c] * ga[c];
    }
    kk[e][0] = k0; kk[e][1] = k1; kk[e][2] = k2;
    vv[e][0] = v0; vv[e][1] = v1; vv[e][2] = v2;
    km[0] = fmaxf(km[0], fabsf(k0));
    km[1] = fmaxf(km[1], fabsf(k1));
    km[2] = fmaxf(km[2], fabsf(k2));
  }
  unsigned* o = (unsigned*)(ws + KVH_OFF) + b * 6144 + pp * 6;
  o[0] = h2_bits(__builtin_amdgcn_cvt_pkrtz(kk[0][0], kk[0][1]));
  o[1] = h2_bits(__builtin_amdgcn_cvt_pkrtz(kk[1][0], kk[1][1]));
  o[2] = h2_bits(__builtin_amdgcn_cvt_pkrtz(kk[0][2], kk[1][2]));
  o[3] = h2_bits(__builtin_amdgcn_cvt_pkrtz(vv[0][0], vv[1][0]));
  o[4] = h2_bits(__builtin_amdgcn_cvt_pkrtz(vv[0][1], vv[1][1]));
  o[5] = h2_bits(__builtin_amdgcn_cvt_pkrtz(vv[0][2], vv[1][2]));

  #pragma unroll
  for (int j = 0; j < 3; j++) km[j] = wave_reduce_max(km[j]);
  if ((threadIdx.x & 63) == 0) {
    unsigned* wsu = (unsigned*)ws;
    #pragma unroll
    for (int j = 0; j < 3; j++)
      atomicMax(&wsu[KMAX_OFF + b * 3 + j], __float_as_uint(km[j]));
  }

  // ---- tiny: k_inter / v_inter for both batches (prep2 merged) ----
  if (blockIdx.x == 0 && threadIdx.x == 0) {
    for (int bb = 0; bb < 2; bb++) {
      float gi[18];
      for (int c = 0; c < 6; c++)
        for (int m = 0; m < 3; m++) {
          float pl = bpl[m];
          for (int k = 0; k < 3; k++)
            pl += Wpl[m * 3 + k] * (ws[CS_OFF + k * 6 + c] * (1.f / LL));
          float Wv = ws[W_OFF + (bb * 3 + m) * 6 + c];
          float sv = ws[MS_OFF + (bb * 3 + m) * 2 + 1];
          gi[c * 3 + m] = Wv / sv + pl;
        }
      for (int m = 0; m < 3; m++)
        for (int k = 0; k < 3; k++) {
          float ki = 0.f, vi = 0.f;
          for (int c = 0; c < 6; c++) {
            ki += Wa [m * 6 + c] * gi[c * 3 + k];
            vi += Wav[m * 6 + c] * gi[c * 3 + k];
          }
          ws[KI_OFF + bb * 9 + m * 3 + k] = ki;
          ws[VI_OFF + bb * 9 + k * 3 + m] = vi;   // [k][m]
        }
    }
  }
}

// ---------------------------------------------------------------- main ----
// 512 blocks x 512 thr. Block = 128 rows, full L staged as f16 pairs (25 KB).
// wv = tid>>6: h = wv>>2 (L-half), rg4 = wv&3. lane: seg = lane&15 (64 keys),
// grp = (lane>>4)&3. Thread: 8 rows x 64 keys, f16 dot2 pipeline.
// launch_bounds(512,4): VGPR cap 128 so the 8-row state (~100 regs) fits
// WITHOUT spilling (R5's 56-VGPR alloc spilled in the hot loop).
__global__ __launch_bounds__(512, 4)
void attn_kernel(const float* __restrict__ x,  const float* __restrict__ Wc,
                 const float* __restrict__ Wd, const float* __restrict__ lng,
                 const float* __restrict__ lnb,
                 float* __restrict__ ws, float* __restrict__ yout)
{
  __shared__ float4 kvs4[32 * 49];    // 25088 B (48 used per 49-slot, stagger pad)
  __shared__ float4 cross4[256];      // [h][r128] {d,p0,p1,p2}
  __shared__ float  cp[8 * 12];
  const int tid  = threadIdx.x;
  const int blk  = blockIdx.x;            // 0..511
  const int lane = tid & 63, wv = tid >> 6;
  const int seg  = lane & 15;
  const int grp  = (lane >> 4) & 3;
  const int h    = wv >> 2;
  const int rg4  = wv & 3;
  const int rbase = blk * 128;
  const int b    = rbase >> 15;
  const int nb   = rbase & (N_PTS - 1);   // block-first row within batch

  // stage f16 pair table: 1536 float4, slot s covers pairs [32s, 32s+32)
  const float4* src = (const float4*)(ws + KVH_OFF) + b * 1536;
  for (int i = tid; i < 1536; i += 512) {
    int s = i / 48, t = i - s * 48;
    kvs4[s * 49 + t] = src[i];
  }
  __syncthreads();

  // q for 8 rows
  const int n0 = nb + rg4 * 32 + grp * 8;
  const float* xb = x + (size_t)b * 6 * N_PTS + n0;
  float q0[8], q1[8], q2[8];
  #pragma unroll
  for (int r = 0; r < 8; r++) q0[r] = q1[r] = q2[r] = 0.f;
  #pragma unroll
  for (int c = 0; c < 6; c++) {
    float4 xa = *(const float4*)(xb + c * N_PTS);
    float4 xc = *(const float4*)(xb + c * N_PTS + 4);
    float wc0 = Wc[c], wc1 = Wc[6 + c], wc2 = Wc[12 + c];
    float xv[8] = {xa.x, xa.y, xa.z, xa.w, xc.x, xc.y, xc.z, xc.w};
    #pragma unroll
    for (int r = 0; r < 8; r++) {
      q0[r] = fmaf(xv[r], wc0, q0[r]);
      q1[r] = fmaf(xv[r], wc1, q1[r]);
      q2[r] = fmaf(xv[r], wc2, q2[r]);
    }
  }
  const float KS = 1.4426950408889634f * 0.57735026918962576f;  // log2e/sqrt(3)
  const float* kmx = ws + KMAX_OFF + b * 3;
  float km0 = kmx[0], km1 = kmx[1], km2 = kmx[2];
  h2 q01h[8], q2A[8], q2B[8];
  float mMp[8];
  #pragma unroll
  for (int r = 0; r < 8; r++) {
    q0[r] *= KS; q1[r] *= KS; q2[r] *= KS;
    q01h[r] = __builtin_amdgcn_cvt_pkrtz(q0[r], q1[r]);
    q2A[r]  = __builtin_amdgcn_cvt_pkrtz(q2[r], 0.f);
    q2B[r]  = __builtin_amdgcn_cvt_pkrtz(0.f, q2[r]);
    mMp[r]  = -(fabsf(q0[r]) * km0 + fabsf(q1[r]) * km1 + fabsf(q2[r]) * km2);
  }

  const h2 one2 = {(__fp16)1.f, (__fp16)1.f};
  float d[8], p0[8], p1[8], p2[8];
  #pragma unroll
  for (int r = 0; r < 8; r++) d[r] = p0[r] = p1[r] = p2[r] = 0.f;

  // 64 keys = 16 iters x 4 keys (2 pair-records = 3 float4)
  const float4* base = &kvs4[(h * 16 + seg) * 49];
  #pragma unroll 2
  for (int j = 0; j < 16; j++) {
    float4 F0 = base[3 * j], F1 = base[3 * j + 1], F2 = base[3 * j + 2];
    union { float4 f; unsigned u[4]; } U0, U1, U2;
    U0.f = F0; U1.f = F1; U2.f = F2;
    h2 k01a = as_h2(U0.u[0]), k01b = as_h2(U0.u[1]), k2ab = as_h2(U0.u[2]);
    h2 v0ab = as_h2(U0.u[3]), v1ab = as_h2(U1.u[0]), v2ab = as_h2(U1.u[1]);
    h2 k01c = as_h2(U1.u[2]), k01d = as_h2(U1.u[3]), k2cd = as_h2(U2.u[0]);
    h2 v0cd = as_h2(U2.u[1]), v1cd = as_h2(U2.u[2]), v2cd = as_h2(U2.u[3]);
    #pragma unroll
    for (int r = 0; r < 8; r++) {
      float sa = __builtin_amdgcn_fdot2(q01h[r], k01a,
                   __builtin_amdgcn_fdot2(q2A[r], k2ab, mMp[r], false), false);
      float sb = __builtin_amdgcn_fdot2(q01h[r], k01b,
                   __builtin_amdgcn_fdot2(q2B[r], k2ab, mMp[r], false), false);
      float sc = __builtin_amdgcn_fdot2(q01h[r], k01c,
                   __builtin_amdgcn_fdot2(q2A[r], k2cd, mMp[r], false), false);
      float sd = __builtin_amdgcn_fdot2(q01h[r], k01d,
                   __builtin_amdgcn_fdot2(q2B[r], k2cd, mMp[r], false), false);
      float ea = __builtin_amdgcn_exp2f(sa);
      float eb = __builtin_amdgcn_exp2f(sb);
      float ec = __builtin_amdgcn_exp2f(sc);
      float ed = __builtin_amdgcn_exp2f(sd);
      h2 eab = __builtin_amdgcn_cvt_pkrtz(ea, eb);
      h2 ecd = __builtin_amdgcn_cvt_pkrtz(ec, ed);
      d[r]  = __builtin_amdgcn_fdot2(eab, one2,
                __builtin_amdgcn_fdot2(ecd, one2, d[r],  false), false);
      p0[r] = __builtin_amdgcn_fdot2(eab, v0ab,
                __builtin_amdgcn_fdot2(ecd, v0cd, p0[r], false), false);
      p1[r] = __builtin_amdgcn_fdot2(eab, v1ab,
                __builtin_amdgcn_fdot2(ecd, v1cd, p1[r], false), false);
      p2[r] = __builtin_amdgcn_fdot2(eab, v2ab,
                __builtin_amdgcn_fdot2(ecd, v2cd, p2[r], false), false);
    }
  }

  // butterfly-combine across the 16 segments (Mp is seg-independent)
  #pragma unroll
  for (int m = 1; m <= 8; m <<= 1) {
    #pragma unroll
    for (int r = 0; r < 8; r++) {
      d[r]  += __shfl_xor(d[r],  m, 64);
      p0[r] += __shfl_xor(p0[r], m, 64);
      p1[r] += __shfl_xor(p1[r], m, 64);
      p2[r] += __shfl_xor(p2[r], m, 64);
    }
  }

  // lane seg<8 publishes row (rg4*32 + grp*8 + seg) for its half h
  if (seg < 8) {
    float dd = 0, w0 = 0, w1 = 0, w2 = 0;
    #pragma unroll
    for (int r = 0; r < 8; r++)
      if (seg == r) { dd = d[r]; w0 = p0[r]; w1 = p1[r]; w2 = p2[r]; }
    cross4[h * 128 + rg4 * 32 + grp * 8 + seg] = make_float4(dd, w0, w1, w2);
  }
  __syncthreads();

  float v12[12];
  #pragma unroll
  for (int j = 0; j < 12; j++) v12[j] = 0.f;

  if (tid < 128) {
    const int r = tid;
    const int n = nb + r;
    float4 c0 = cross4[r], c1 = cross4[128 + r];
    float dd = c0.x + c1.x, w0 = c0.y + c1.y, w1 = c0.z + c1.z, w2 = c0.w + c1.w;

    // recompute q (scaled)
    const float* xr = x + (size_t)b * 6 * N_PTS + n;
    float a0 = 0, a1 = 0, a2 = 0;
    #pragma unroll
    for (int c = 0; c < 6; c++) {
      float xv = xr[c * N_PTS];
      a0 = fmaf(xv, Wc[c], a0); a1 = fmaf(xv, Wc[6 + c], a1); a2 = fmaf(xv, Wc[12 + c], a2);
    }
    a0 *= KS; a1 *= KS; a2 *= KS;

    const float* ki = ws + KI_OFF + b * 9;
    const float* vi = ws + VI_OFF + b * 9;
    float sk0 = a0 * ki[0] + a1 * ki[3] + a2 * ki[6];
    float sk1 = a0 * ki[1] + a1 * ki[4] + a2 * ki[7];
    float sk2 = a0 * ki[2] + a1 * ki[5] + a2 * ki[8];
    float mm  = fmaxf(fmaxf(sk0, sk1), sk2);
    float e0 = __builtin_amdgcn_exp2f(sk0 - mm);
    float e1 = __builtin_amdgcn_exp2f(sk1 - mm);
    float e2 = __builtin_amdgcn_exp2f(sk2 - mm);
    float rs = 1.f / (e0 + e1 + e2);
    float fi0 = (e0 * vi[0] + e1 * vi[3] + e2 * vi[6]) * rs;
    float fi1 = (e0 * vi[1] + e1 * vi[4] + e2 * vi[7]) * rs;
    float fi2 = (e0 * vi[2] + e1 * vi[5] + e2 * vi[8]) * rs;
    float rinv = 1.f / dd;
    float cf[6] = { fi0, fi1, fi2, w0 * rinv, w1 * rinv, w2 * rinv };

    float mu = (cf[0] + cf[1] + cf[2] + cf[3] + cf[4] + cf[5]) * (1.f / 6.f);
    float var = 0.f;
    #pragma unroll
    for (int i = 0; i < 6; i++) { float t = cf[i] - mu; var += t * t; }
    var *= (1.f / 6.f);
    float rn = rsqrtf(var + 1e-5f);
    float cfn[6];
    #pragma unroll
    for (int i = 0; i < 6; i++) cfn[i] = (cf[i] - mu) * rn * lng[i] + lnb[i];

    #pragma unroll
    for (int o = 0; o < 6; o++) {
      float s = 0.f;
      #pragma unroll
      for (int c = 0; c < 6; c++) s += Wd[o * 6 + c] * cfn[c];
      yout[(size_t)b * (6 * N_PTS) + o * N_PTS + n] = s;
      v12[o] = s; v12[6 + o] = s * s;
    }
  }

  // deterministic BN partials (per block)
  #pragma unroll
  for (int j = 0; j < 12; j++) v12[j] = wave_reduce_sum(v12[j]);
  if (lane == 0) { for (int j = 0; j < 12; j++) cp[wv * 12 + j] = v12[j]; }
  __syncthreads();
  if (tid == 0) {
    float* part = ws + PART_OFF + blk * 12;
    for (int j = 0; j < 12; j++) {
      float s = 0.f;
      for (int w = 0; w < 8; w++) s += cp[w * 12 + j];
      part[j] = s;
    }
  }
}

// ------------------------------------------------------------- bn stats ---
__global__ __launch_bounds__(256)
void bnstats_kernel(const float* __restrict__ bng, const float* __restrict__ bnbt,
                    float* __restrict__ ws)
{
  __shared__ float cp[48];
  const int tid = threadIdx.x;
  const float* part = ws + PART_OFF;
  float v[12];
  #pragma unroll
  for (int j = 0; j < 12; j++)
    v[j] = part[tid * 12 + j] + part[(tid + 256) * 12 + j];
  #pragma unroll
  for (int j = 0; j < 12; j++) v[j] = wave_reduce_sum(v[j]);
  const int lane = tid & 63, wid = tid >> 6;
  if (lane == 0) { for (int j = 0; j < 12; j++) cp[wid * 12 + j] = v[j]; }
  __syncthreads();
  if (tid == 0) {
    const float inv = 1.f / 65536.f;   // B * N
    for (int o = 0; o < 6; o++) {
      float s1 = cp[o] + cp[12 + o] + cp[24 + o] + cp[36 + o];
      float s2 = cp[6 + o] + cp[18 + o] + cp[30 + o] + cp[42 + o];
      float mean = s1 * inv;
      float varr = s2 * inv - mean * mean;
      float sc = bng[o] * rsqrtf(varr + 1e-5f);
      ws[BNS_OFF + o] = sc;
      ws[BNB_OFF + o] = bnbt[o] - mean * sc;
    }
  }
}

// ------------------------------------------------------------- finalize ---
__global__ __launch_bounds__(256)
void final_kernel(const float* __restrict__ x, const float* __restrict__ ws,
                  float* __restrict__ out)
{
  const int i = blockIdx.x * 256 + threadIdx.x;   // 393216 total
  const int ch = (i >> 15) % 6;
  float v = out[i] * ws[BNS_OFF + ch] + ws[BNB_OFF + ch] + x[i];
  out[i] = v >= 0.f ? v : 0.2f * v;
}

// ---------------------------------------------------------------- launch --
extern "C" void kernel_launch(void* const* d_in, const int* in_sizes, int n_in,
                              void* d_out, int out_size, void* d_ws, size_t ws_size,
                              hipStream_t stream)
{
  const float* x      = (const float*)d_in[0];
  const float* curves = (const float*)d_in[1];
  const float* Wa     = (const float*)d_in[2];
  const float* Wav    = (const float*)d_in[3];
  const float* Wb     = (const float*)d_in[4];
  const float* Wbv    = (const float*)d_in[5];
  const float* Wc     = (const float*)d_in[6];
  const float* Wd     = (const float*)d_in[7];
  const float* bng    = (const float*)d_in[8];
  const float* bnbt   = (const float*)d_in[9];
  const float* Watt   = (const float*)d_in[10];
  const float* lng    = (const float*)d_in[11];
  const float* lnbt   = (const float*)d_in[12];
  const float* Wpl    = (const float*)d_in[13];
  const float* bpl    = (const float*)d_in[14];
  const float* Wpn    = (const float*)d_in[15];
  const float* bpn    = (const float*)d_in[16];
  float* out = (float*)d_out;
  float* ws  = (float*)d_ws;

  prep1_kernel<<<6, 512, 0, stream>>>(curves, Watt, ws);
  kv_kernel<<<16, 128, 0, stream>>>(curves, Wa, Wav, Wb, Wbv,
                                    Wpl, bpl, Wpn, bpn, ws);
  attn_kernel<<<512, 512, 0, stream>>>(x, Wc, Wd, lng, lnbt, ws, out);
  bnstats_kernel<<<1, 256, 0, stream>>>(bng, bnbt, ws);
  final_kernel<<<1536, 256, 0, stream>>>(x, ws, out);
}

// Round 7
// 44.033 us; speedup vs baseline: 1.7930x; 1.3232x over previous
//
#include <hip/hip_runtime.h>
#include <math.h>

#define N_PTS 32768
#define LL    2048

// d_ws dword/float offsets
#define KT_U      0          // uint: [2][2048][2]  K frag table (k0k1, k2_0)
#define VT_U      8192       // uint: [2][4][1024]  V planes (v0,v1,v2,ones) f16-pairs
#define ATT_OFF   16384      // float [6][2048] att scores (aliased by PART later)
#define PART_OFF  16384      // [1024][12] BN partials — aliases ATT (ATT dead by then)
#define KI_OFF    28672      // [2][3][3]
#define VI_OFF    28690      // [2][3][3]
#define KMAX_OFF  28708      // [2][3] uint-bits atomic max
#define MS_OFF    28714      // [6][2]
#define W_OFF     28726      // [6][6]
#define CS_OFF    28762      // [3][6]
#define BNS_OFF   28780      // [6]
#define BNB_OFF   28786      // [6]

typedef __fp16 h2    __attribute__((ext_vector_type(2)));
typedef __fp16 f16x4 __attribute__((ext_vector_type(4)));
typedef float  f32x4 __attribute__((ext_vector_type(4)));

__device__ __forceinline__ unsigned h2_bits(h2 h){
  union { h2 h; unsigned u; } x; x.h = h; return x.u;
}
__device__ __forceinline__ float wave_reduce_sum(float v){
  #pragma unroll
  for (int off = 32; off; off >>= 1) v += __shfl_xor(v, off, 64);
  return v;
}
__device__ __forceinline__ float wave_reduce_max(float v){
  #pragma unroll
  for (int off = 32; off; off >>= 1) v = fmaxf(v, __shfl_xor(v, off, 64));
  return v;
}

// --------------------------------------------------------------- prep1 ----
__global__ __launch_bounds__(512)
void prep1_kernel(const float* __restrict__ curves,
                  const float* __restrict__ Watt, float* __restrict__ ws)
{
  const int blk = blockIdx.x;          // b*3 + nc
  const int b = blk / 3, nc = blk % 3;
  const int tid = threadIdx.x, lane = tid & 63, wid = tid >> 6;
  __shared__ float sred[8 * 13];
  __shared__ float mshare;

  float watt[6];
  #pragma unroll
  for (int c = 0; c < 6; c++) watt[c] = Watt[c];
  const float* cb = curves + b * 6 * 3 * LL;

  float av[4], cbv[4][6];
  #pragma unroll
  for (int k = 0; k < 4; k++) {
    const int l = tid + k * 512;
    float s = 0.f;
    #pragma unroll
    for (int c = 0; c < 6; c++) {
      float v = cb[(c * 3 + nc) * LL + l];
      cbv[k][c] = v;
      s = fmaf(v, watt[c], s);
    }
    av[k] = s;
    ws[ATT_OFF + blk * LL + l] = s;
  }
  float pm = fmaxf(fmaxf(av[0], av[1]), fmaxf(av[2], av[3]));
  pm = wave_reduce_max(pm);
  if (lane == 0) sred[wid] = pm;
  __syncthreads();
  if (tid == 0) {
    float m = sred[0];
    for (int w = 1; w < 8; w++) m = fmaxf(m, sred[w]);
    mshare = m;
  }
  __syncthreads();
  const float m = mshare;

  float vals[13];
  #pragma unroll
  for (int j = 0; j < 13; j++) vals[j] = 0.f;
  #pragma unroll
  for (int k = 0; k < 4; k++) {
    float e = __expf(av[k] - m);
    vals[0] += e;
    #pragma unroll
    for (int c = 0; c < 6; c++) {
      vals[1 + c] = fmaf(cbv[k][c], e, vals[1 + c]);
      if (b == 0) vals[7 + c] += cbv[k][c];
    }
  }
  #pragma unroll
  for (int j = 0; j < 13; j++) vals[j] = wave_reduce_sum(vals[j]);
  if (lane == 0) { for (int j = 0; j < 13; j++) sred[wid * 13 + j] = vals[j]; }
  __syncthreads();
  if (tid == 0) {
    float t[13];
    for (int j = 0; j < 13; j++) {
      float s = 0.f;
      for (int w = 0; w < 8; w++) s += sred[w * 13 + j];
      t[j] = s;
    }
    ws[MS_OFF + blk * 2]     = m;
    ws[MS_OFF + blk * 2 + 1] = t[0];
    for (int c = 0; c < 6; c++) ws[W_OFF + blk * 6 + c] = t[1 + c];
    if (b == 0) for (int c = 0; c < 6; c++) ws[CS_OFF + nc * 6 + c] = t[7 + c];
  }
  if (blk == 0 && tid < 6) ((unsigned*)ws)[KMAX_OFF + tid] = 0u;
}

// ------------------------------------------------------------------ kv ----
// One key-PAIR per thread. Writes MFMA-friendly tables: KT (per l: k0k1,k2_0)
// and VT (4 f16 planes: v0,v1,v2,ones). Block 0 thread 0 does k/v_inter.
__global__ __launch_bounds__(128)
void kv_kernel(const float* __restrict__ curves,
               const float* __restrict__ Wa,  const float* __restrict__ Wav,
               const float* __restrict__ Wb,  const float* __restrict__ Wbv,
               const float* __restrict__ Wpl, const float* __restrict__ bpl,
               const float* __restrict__ Wpn, const float* __restrict__ bpn,
               float* __restrict__ ws)
{
  const int idx = blockIdx.x * 128 + threadIdx.x;   // 0..2047
  const int b = idx >> 10, pp = idx & 1023, l = pp * 2;
  const float* cb = curves + b * 6 * 3 * LL;

  float2 a[3];
  #pragma unroll
  for (int nc = 0; nc < 3; nc++)
    a[nc] = *(const float2*)&ws[ATT_OFF + (b * 3 + nc) * LL + l];

  float2 cv[6][3], pv[6][3];
  #pragma unroll
  for (int c = 0; c < 6; c++)
    #pragma unroll
    for (int nc = 0; nc < 3; nc++) {
      cv[c][nc] = *(const float2*)&cb[(c * 3 + nc) * LL + l];
      pv[c][nc] = *(const float2*)&curves[(c * 3 + nc) * LL + l];  // batch 0
    }

  float wb_r[18], wbv_r[18];
  #pragma unroll
  for (int i = 0; i < 18; i++) { wb_r[i] = Wb[i]; wbv_r[i] = Wbv[i]; }
  const float wn0 = (Wpn[0] + Wpn[3] + Wpn[6]) * (1.f / 3.f);
  const float wn1 = (Wpn[1] + Wpn[4] + Wpn[7]) * (1.f / 3.f);
  const float wn2 = (Wpn[2] + Wpn[5] + Wpn[8]) * (1.f / 3.f);
  const float bnb = (bpn[0] + bpn[1] + bpn[2]) * (1.f / 3.f);

  float kk[2][3], vv[2][3], km[3] = {0.f, 0.f, 0.f};
  #pragma unroll
  for (int e = 0; e < 2; e++) {
    float a0 = e ? a[0].y : a[0].x;
    float a1 = e ? a[1].y : a[1].x;
    float a2 = e ? a[2].y : a[2].x;
    float mm = fmaxf(fmaxf(a0, a1), a2);
    float e0 = __expf(a0 - mm), e1 = __expf(a1 - mm), e2 = __expf(a2 - mm);
    float r = 1.f / (e0 + e1 + e2);
    float ga[6];
    #pragma unroll
    for (int c = 0; c < 6; c++) {
      float c0 = e ? cv[c][0].y : cv[c][0].x;
      float c1 = e ? cv[c][1].y : cv[c][1].x;
      float c2 = e ? cv[c][2].y : cv[c][2].x;
      float p0 = e ? pv[c][0].y : pv[c][0].x;
      float p1 = e ? pv[c][1].y : pv[c][1].x;
      float p2 = e ? pv[c][2].y : pv[c][2].x;
      float intra = (c0 * e0 + c1 * e1 + c2 * e2) * r;
      float pn = p0 * wn0 + p1 * wn1 + p2 * wn2 + bnb;
      ga[c] = intra + pn;
    }
    float k0 = 0, k1 = 0, k2 = 0, v0 = 0, v1 = 0, v2 = 0;
    #pragma unroll
    for (int c = 0; c < 6; c++) {
      k0 += wb_r[c] * ga[c];  k1 += wb_r[6 + c] * ga[c];  k2 += wb_r[12 + c] * ga[c];
      v0 += wbv_r[c] * ga[c]; v1 += wbv_r[6 + c] * ga[c]; v2 += wbv_r[12 + c] * ga[c];
    }
    kk[e][0] = k0; kk[e][1] = k1; kk[e][2] = k2;
    vv[e][0] = v0; vv[e][1] = v1; vv[e][2] = v2;
    km[0] = fmaxf(km[0], fabsf(k0));
    km[1] = fmaxf(km[1], fabsf(k1));
    km[2] = fmaxf(km[2], fabsf(k2));
  }
  unsigned* ktg = (unsigned*)ws + KT_U + b * 4096;
  ktg[4 * pp + 0] = h2_bits(__builtin_amdgcn_cvt_pkrtz(kk[0][0], kk[0][1]));
  ktg[4 * pp + 1] = h2_bits(__builtin_amdgcn_cvt_pkrtz(kk[0][2], 0.f));
  ktg[4 * pp + 2] = h2_bits(__builtin_amdgcn_cvt_pkrtz(kk[1][0], kk[1][1]));
  ktg[4 * pp + 3] = h2_bits(__builtin_amdgcn_cvt_pkrtz(kk[1][2], 0.f));
  unsigned* vtg = (unsigned*)ws + VT_U + b * 4096;
  vtg[0 * 1024 + pp] = h2_bits(__builtin_amdgcn_cvt_pkrtz(vv[0][0], vv[1][0]));
  vtg[1 * 1024 + pp] = h2_bits(__builtin_amdgcn_cvt_pkrtz(vv[0][1], vv[1][1]));
  vtg[2 * 1024 + pp] = h2_bits(__builtin_amdgcn_cvt_pkrtz(vv[0][2], vv[1][2]));
  vtg[3 * 1024 + pp] = h2_bits(__builtin_amdgcn_cvt_pkrtz(1.f, 1.f));

  #pragma unroll
  for (int j = 0; j < 3; j++) km[j] = wave_reduce_max(km[j]);
  if ((threadIdx.x & 63) == 0) {
    unsigned* wsu = (unsigned*)ws;
    #pragma unroll
    for (int j = 0; j < 3; j++)
      atomicMax(&wsu[KMAX_OFF + b * 3 + j], __float_as_uint(km[j]));
  }

  if (blockIdx.x == 0 && threadIdx.x == 0) {
    for (int bb = 0; bb < 2; bb++) {
      float gi[18];
      for (int c = 0; c < 6; c++)
        for (int m = 0; m < 3; m++) {
          float pl = bpl[m];
          for (int k = 0; k < 3; k++)
            pl += Wpl[m * 3 + k] * (ws[CS_OFF + k * 6 + c] * (1.f / LL));
          float Wv = ws[W_OFF + (bb * 3 + m) * 6 + c];
          float sv = ws[MS_OFF + (bb * 3 + m) * 2 + 1];
          gi[c * 3 + m] = Wv / sv + pl;
        }
      for (int m = 0; m < 3; m++)
        for (int k = 0; k < 3; k++) {
          float ki = 0.f, vi = 0.f;
          for (int c = 0; c < 6; c++) {
            ki += Wa [m * 6 + c] * gi[c * 3 + k];
            vi += Wav[m * 6 + c] * gi[c * 3 + k];
          }
          ws[KI_OFF + bb * 9 + m * 3 + k] = ki;
          ws[VI_OFF + bb * 9 + k * 3 + m] = vi;   // [k][m]
        }
    }
  }
}

// ---------------------------------------------------------------- main ----
// MFMA formulation. 1024 blocks x 256 thr (4 waves); wave = 16 q-rows.
// Per 16-key chunk: S^T = mfma_16x16x16_f16(A=K-frag, B=Q-frag, C=-Mp);
// P = exp2(S^T); PV via mfma(A=V-frag(+ones row -> denominator), B=P).
// C/D layout (col=lane&15,row=4*hi4+reg) == B layout (col=lane&15,k=4*hi4+j)
// so P feeds the second MFMA with just 2 cvt_pkrtz. Epilogue lane-local.
__global__ __launch_bounds__(256, 4)
void attn_kernel(const float* __restrict__ x,  const float* __restrict__ Wc,
                 const float* __restrict__ Wd, const float* __restrict__ lng,
                 const float* __restrict__ lnb,
                 float* __restrict__ ws, float* __restrict__ yout)
{
  __shared__ __align__(16) unsigned kt[4100];       // [2048][2] + zero pad @4096
  __shared__ __align__(16) unsigned vt[4116];       // 4 planes x 1028 + zero pad @4112
  __shared__ float cp[4 * 12];
  const int tid  = threadIdx.x;
  const int blk  = blockIdx.x;            // 0..1023
  const int lane = tid & 63, wv = tid >> 6;
  const int col  = lane & 15;             // q-col within tile
  const int hi4  = lane >> 4;             // 0..3
  const int rbase = blk * 64;
  const int b    = rbase >> 15;
  const int n0w  = (rbase & (N_PTS - 1)) + wv * 16;
  const int n    = n0w + col;

  // ---- stage K/V tables (16 KB + 16.1 KB) ----
  {
    const uint4* ktg = (const uint4*)((const unsigned*)ws + KT_U + b * 4096);
    uint4* kt4 = (uint4*)kt;
    for (int i = tid; i < 1024; i += 256) kt4[i] = ktg[i];
    const unsigned* vtg = (const unsigned*)ws + VT_U + b * 4096;
    for (int i = tid; i < 4096; i += 256) vt[(i >> 10) * 1028 + (i & 1023)] = vtg[i];
    if (tid < 2) { kt[4096 + tid] = 0; vt[4112 + tid] = 0; }
  }
  __syncthreads();

  // ---- q for this lane's column ----
  const float* xb = x + (size_t)b * 6 * N_PTS + n;
  float q0 = 0, q1 = 0, q2 = 0;
  #pragma unroll
  for (int c = 0; c < 6; c++) {
    float xv = xb[c * N_PTS];
    q0 = fmaf(xv, Wc[c], q0); q1 = fmaf(xv, Wc[6 + c], q1); q2 = fmaf(xv, Wc[12 + c], q2);
  }
  const float KS = 1.4426950408889634f * 0.57735026918962576f;  // log2e/sqrt(3)
  q0 *= KS; q1 *= KS; q2 *= KS;
  const float* kmx = ws + KMAX_OFF + b * 3;
  const float Mp = fabsf(q0) * kmx[0] + fabsf(q1) * kmx[1] + fabsf(q2) * kmx[2];

  union U2 { uint2 u; f16x4 h; };
  U2 qb; qb.u.x = 0; qb.u.y = 0;
  if (hi4 == 0) {
    qb.u.x = h2_bits(__builtin_amdgcn_cvt_pkrtz(q0, q1));
    qb.u.y = h2_bits(__builtin_amdgcn_cvt_pkrtz(q2, 0.f));
  }
  f32x4 cbias = { -Mp, -Mp, -Mp, -Mp };
  f32x4 oacc  = { 0.f, 0.f, 0.f, 0.f };

  // per-chunk LDS dword indices (zero-pad redirect for inactive lanes)
  unsigned ki_ = (hi4 == 0) ? (unsigned)(col * 2) : 4096u;
  const unsigned kdelta = (hi4 == 0) ? 32u : 0u;
  unsigned vi_ = (col < 4) ? (unsigned)(col * 1028 + 2 * hi4) : 4112u;
  const unsigned vdelta = (col < 4) ? 8u : 0u;

  #pragma unroll 4
  for (int ch = 0; ch < 128; ++ch) {
    U2 A; A.u = *(const uint2*)&kt[ki_];
    f32x4 s = __builtin_amdgcn_mfma_f32_16x16x16f16(A.h, qb.h, cbias, 0, 0, 0);
    float e0 = __builtin_amdgcn_exp2f(s[0]);
    float e1 = __builtin_amdgcn_exp2f(s[1]);
    float e2 = __builtin_amdgcn_exp2f(s[2]);
    float e3 = __builtin_amdgcn_exp2f(s[3]);
    U2 P;
    P.u.x = h2_bits(__builtin_amdgcn_cvt_pkrtz(e0, e1));
    P.u.y = h2_bits(__builtin_amdgcn_cvt_pkrtz(e2, e3));
    U2 V; V.u = *(const uint2*)&vt[vi_];
    oacc = __builtin_amdgcn_mfma_f32_16x16x16f16(V.h, P.h, oacc, 0, 0, 0);
    ki_ += kdelta; vi_ += vdelta;
  }

  // ---- epilogue: lanes hi4==0 own (p0,p1,p2,d) for row n ----
  float v12[12];
  #pragma unroll
  for (int j = 0; j < 12; j++) v12[j] = 0.f;

  if (hi4 == 0) {
    float w0 = oacc[0], w1 = oacc[1], w2 = oacc[2], dd = oacc[3];
    const float* ki = ws + KI_OFF + b * 9;
    const float* vi = ws + VI_OFF + b * 9;
    float sk0 = q0 * ki[0] + q1 * ki[3] + q2 * ki[6];
    float sk1 = q0 * ki[1] + q1 * ki[4] + q2 * ki[7];
    float sk2 = q0 * ki[2] + q1 * ki[5] + q2 * ki[8];
    float mm  = fmaxf(fmaxf(sk0, sk1), sk2);
    float e0 = __builtin_amdgcn_exp2f(sk0 - mm);
    float e1 = __builtin_amdgcn_exp2f(sk1 - mm);
    float e2 = __builtin_amdgcn_exp2f(sk2 - mm);
    float rs = 1.f / (e0 + e1 + e2);
    float fi0 = (e0 * vi[0] + e1 * vi[3] + e2 * vi[6]) * rs;
    float fi1 = (e0 * vi[1] + e1 * vi[4] + e2 * vi[7]) * rs;
    float fi2 = (e0 * vi[2] + e1 * vi[5] + e2 * vi[8]) * rs;
    float rinv = 1.f / dd;
    float cf[6] = { fi0, fi1, fi2, w0 * rinv, w1 * rinv, w2 * rinv };

    float mu = (cf[0] + cf[1] + cf[2] + cf[3] + cf[4] + cf[5]) * (1.f / 6.f);
    float var = 0.f;
    #pragma unroll
    for (int i = 0; i < 6; i++) { float t = cf[i] - mu; var += t * t; }
    var *= (1.f / 6.f);
    float rn = rsqrtf(var + 1e-5f);
    float cfn[6];
    #pragma unroll
    for (int i = 0; i < 6; i++) cfn[i] = (cf[i] - mu) * rn * lng[i] + lnb[i];

    #pragma unroll
    for (int o = 0; o < 6; o++) {
      float s = 0.f;
      #pragma unroll
      for (int c = 0; c < 6; c++) s += Wd[o * 6 + c] * cfn[c];
      yout[(size_t)b * (6 * N_PTS) + o * N_PTS + n] = s;
      v12[o] = s; v12[6 + o] = s * s;
    }
  }

  // deterministic BN partials (per block)
  #pragma unroll
  for (int j = 0; j < 12; j++) v12[j] = wave_reduce_sum(v12[j]);
  if (lane == 0) { for (int j = 0; j < 12; j++) cp[wv * 12 + j] = v12[j]; }
  __syncthreads();
  if (tid == 0) {
    float* part = ws + PART_OFF + blk * 12;
    for (int j = 0; j < 12; j++)
      part[j] = cp[j] + cp[12 + j] + cp[24 + j] + cp[36 + j];
  }
}

// ------------------------------------------------------------- bn stats ---
__global__ __launch_bounds__(256)
void bnstats_kernel(const float* __restrict__ bng, const float* __restrict__ bnbt,
                    float* __restrict__ ws)
{
  __shared__ float cp[48];
  const int tid = threadIdx.x;
  const float* part = ws + PART_OFF;
  float v[12];
  #pragma unroll
  for (int j = 0; j < 12; j++)
    v[j] = part[tid * 12 + j] + part[(tid + 256) * 12 + j]
         + part[(tid + 512) * 12 + j] + part[(tid + 768) * 12 + j];
  #pragma unroll
  for (int j = 0; j < 12; j++) v[j] = wave_reduce_sum(v[j]);
  const int lane = tid & 63, wid = tid >> 6;
  if (lane == 0) { for (int j = 0; j < 12; j++) cp[wid * 12 + j] = v[j]; }
  __syncthreads();
  if (tid == 0) {
    const float inv = 1.f / 65536.f;   // B * N
    for (int o = 0; o < 6; o++) {
      float s1 = cp[o] + cp[12 + o] + cp[24 + o] + cp[36 + o];
      float s2 = cp[6 + o] + cp[18 + o] + cp[30 + o] + cp[42 + o];
      float mean = s1 * inv;
      float varr = s2 * inv - mean * mean;
      float sc = bng[o] * rsqrtf(varr + 1e-5f);
      ws[BNS_OFF + o] = sc;
      ws[BNB_OFF + o] = bnbt[o] - mean * sc;
    }
  }
}

// ------------------------------------------------------------- finalize ---
__global__ __launch_bounds__(256)
void final_kernel(const float* __restrict__ x, const float* __restrict__ ws,
                  float* __restrict__ out)
{
  const int i = blockIdx.x * 256 + threadIdx.x;   // 393216 total
  const int ch = (i >> 15) % 6;
  float v = out[i] * ws[BNS_OFF + ch] + ws[BNB_OFF + ch] + x[i];
  out[i] = v >= 0.f ? v : 0.2f * v;
}

// ---------------------------------------------------------------- launch --
extern "C" void kernel_launch(void* const* d_in, const int* in_sizes, int n_in,
                              void* d_out, int out_size, void* d_ws, size_t ws_size,
                              hipStream_t stream)
{
  const float* x      = (const float*)d_in[0];
  const float* curves = (const float*)d_in[1];
  const float* Wa     = (const float*)d_in[2];
  const float* Wav    = (const float*)d_in[3];
  const float* Wb     = (const float*)d_in[4];
  const float* Wbv    = (const float*)d_in[5];
  const float* Wc     = (const float*)d_in[6];
  const float* Wd     = (const float*)d_in[7];
  const float* bng    = (const float*)d_in[8];
  const float* bnbt   = (const float*)d_in[9];
  const float* Watt   = (const float*)d_in[10];
  const float* lng    = (const float*)d_in[11];
  const float* lnbt   = (const float*)d_in[12];
  const float* Wpl    = (const float*)d_in[13];
  const float* bpl    = (const float*)d_in[14];
  const float* Wpn    = (const float*)d_in[15];
  const float* bpn    = (const float*)d_in[16];
  float* out = (float*)d_out;
  float* ws  = (float*)d_ws;

  prep1_kernel<<<6, 512, 0, stream>>>(curves, Watt, ws);
  kv_kernel<<<16, 128, 0, stream>>>(curves, Wa, Wav, Wb, Wbv,
                                    Wpl, bpl, Wpn, bpn, ws);
  attn_kernel<<<1024, 256, 0, stream>>>(x, Wc, Wd, lng, lnbt, ws, out);
  bnstats_kernel<<<1, 256, 0, stream>>>(bng, bnbt, ws);
  final_kernel<<<1536, 256, 0, stream>>>(x, ws, out);
}

// Round 8
// 34.549 us; speedup vs baseline: 2.2852x; 1.2745x over previous
//
#include <hip/hip_runtime.h>
#include <math.h>

#define N_PTS 32768
#define LL    2048

// d_ws dword/float offsets
#define KT_U      0          // uint: [2][2048][2] K frag table {k0k1, k2_0}
#define VT_U      8192       // uint: [2][4][1024] V planes (v0,v1,v2,ones) f16-pairs
#define PART_OFF  16384      // float [1024][12] BN partials
#define MS_OFF    28672      // [6][2]  {m, expsum}
#define W_OFF     28684      // [6][6]  exp-weighted sums
#define CS_OFF    28720      // [3][6]  colsum batch0
#define PBKM_OFF  28738      // [8][3]  per-kvblock |k| max
#define BNS_OFF   28762      // [6]
#define BNB_OFF   28768      // [6]

typedef __fp16 h2    __attribute__((ext_vector_type(2)));
typedef __fp16 f16x4 __attribute__((ext_vector_type(4)));
typedef float  f32x4 __attribute__((ext_vector_type(4)));

__device__ __forceinline__ unsigned h2_bits(h2 h){
  union { h2 h; unsigned u; } x; x.h = h; return x.u;
}
__device__ __forceinline__ float wave_reduce_sum(float v){
  #pragma unroll
  for (int off = 32; off; off >>= 1) v += __shfl_xor(v, off, 64);
  return v;
}
__device__ __forceinline__ float wave_reduce_max(float v){
  #pragma unroll
  for (int off = 32; off; off >>= 1) v = fmaxf(v, __shfl_xor(v, off, 64));
  return v;
}

// ---------------------------------------------------------------- prep ----
// 14 blocks x 256. Blocks 0-5: per-(b,nc) global stats (max, expsum, W, CS).
// Blocks 6-13: kv table build (att recomputed locally); per-block |k| max
// into PBKM slots (no atomics).
__global__ __launch_bounds__(256)
void prep_kernel(const float* __restrict__ curves, const float* __restrict__ Watt,
                 const float* __restrict__ Wb,  const float* __restrict__ Wbv,
                 const float* __restrict__ Wpn, const float* __restrict__ bpn,
                 float* __restrict__ ws)
{
  const int blk = blockIdx.x, tid = threadIdx.x;
  const int lane = tid & 63, wid = tid >> 6;
  __shared__ float sred[4 * 13];
  __shared__ float msh;

  float watt[6];
  #pragma unroll
  for (int c = 0; c < 6; c++) watt[c] = Watt[c];

  if (blk < 6) {
    const int b = blk / 3, nc = blk % 3;
    const float* cb = curves + b * 18 * LL;
    float av[8], pm = -1e30f;
    #pragma unroll
    for (int k = 0; k < 8; k++) {
      const int l = tid + k * 256;
      float s = 0.f;
      #pragma unroll
      for (int c = 0; c < 6; c++) s = fmaf(cb[(c * 3 + nc) * LL + l], watt[c], s);
      av[k] = s; pm = fmaxf(pm, s);
    }
    pm = wave_reduce_max(pm);
    if (lane == 0) sred[wid] = pm;
    __syncthreads();
    if (tid == 0) msh = fmaxf(fmaxf(sred[0], sred[1]), fmaxf(sred[2], sred[3]));
    __syncthreads();
    const float m = msh;

    float vals[13];
    #pragma unroll
    for (int j = 0; j < 13; j++) vals[j] = 0.f;
    #pragma unroll
    for (int k = 0; k < 8; k++) {
      const int l = tid + k * 256;
      float e = __expf(av[k] - m);
      vals[0] += e;
      #pragma unroll
      for (int c = 0; c < 6; c++) {
        float v = cb[(c * 3 + nc) * LL + l];
        vals[1 + c] = fmaf(v, e, vals[1 + c]);
        if (b == 0) vals[7 + c] += v;
      }
    }
    __syncthreads();
    #pragma unroll
    for (int j = 0; j < 13; j++) vals[j] = wave_reduce_sum(vals[j]);
    if (lane == 0) { for (int j = 0; j < 13; j++) sred[wid * 13 + j] = vals[j]; }
    __syncthreads();
    if (tid == 0) {
      ws[MS_OFF + blk * 2] = m;
      for (int j = 0; j < 13; j++) {
        float s = sred[j] + sred[13 + j] + sred[26 + j] + sred[39 + j];
        if (j == 0) ws[MS_OFF + blk * 2 + 1] = s;
        else if (j < 7) ws[W_OFF + blk * 6 + (j - 1)] = s;
        else if (b == 0) ws[CS_OFF + nc * 6 + (j - 7)] = s;
      }
    }
  } else {
    const int idx = (blk - 6) * 256 + tid;   // 0..2047
    const int b = idx >> 10, pp = idx & 1023, l = pp * 2;
    const float* cb = curves + b * 18 * LL;

    float2 cv[6][3], pv[6][3];
    #pragma unroll
    for (int c = 0; c < 6; c++)
      #pragma unroll
      for (int nc = 0; nc < 3; nc++) {
        cv[c][nc] = *(const float2*)&cb[(c * 3 + nc) * LL + l];
        pv[c][nc] = *(const float2*)&curves[(c * 3 + nc) * LL + l];  // batch 0
      }
    float a[3][2];
    #pragma unroll
    for (int nc = 0; nc < 3; nc++) {
      float sx = 0.f, sy = 0.f;
      #pragma unroll
      for (int c = 0; c < 6; c++) {
        sx = fmaf(cv[c][nc].x, watt[c], sx);
        sy = fmaf(cv[c][nc].y, watt[c], sy);
      }
      a[nc][0] = sx; a[nc][1] = sy;
    }

    float wb_r[18], wbv_r[18];
    #pragma unroll
    for (int i = 0; i < 18; i++) { wb_r[i] = Wb[i]; wbv_r[i] = Wbv[i]; }
    const float wn0 = (Wpn[0] + Wpn[3] + Wpn[6]) * (1.f / 3.f);
    const float wn1 = (Wpn[1] + Wpn[4] + Wpn[7]) * (1.f / 3.f);
    const float wn2 = (Wpn[2] + Wpn[5] + Wpn[8]) * (1.f / 3.f);
    const float bnb = (bpn[0] + bpn[1] + bpn[2]) * (1.f / 3.f);

    float kk[2][3], vv[2][3], km[3] = {0.f, 0.f, 0.f};
    #pragma unroll
    for (int e = 0; e < 2; e++) {
      float a0 = a[0][e], a1 = a[1][e], a2 = a[2][e];
      float mm = fmaxf(fmaxf(a0, a1), a2);
      float e0 = __expf(a0 - mm), e1 = __expf(a1 - mm), e2 = __expf(a2 - mm);
      float r = 1.f / (e0 + e1 + e2);
      float ga[6];
      #pragma unroll
      for (int c = 0; c < 6; c++) {
        float c0 = e ? cv[c][0].y : cv[c][0].x;
        float c1 = e ? cv[c][1].y : cv[c][1].x;
        float c2 = e ? cv[c][2].y : cv[c][2].x;
        float p0 = e ? pv[c][0].y : pv[c][0].x;
        float p1 = e ? pv[c][1].y : pv[c][1].x;
        float p2 = e ? pv[c][2].y : pv[c][2].x;
        float intra = (c0 * e0 + c1 * e1 + c2 * e2) * r;
        float pn = p0 * wn0 + p1 * wn1 + p2 * wn2 + bnb;
        ga[c] = intra + pn;
      }
      float k0 = 0, k1 = 0, k2 = 0, v0 = 0, v1 = 0, v2 = 0;
      #pragma unroll
      for (int c = 0; c < 6; c++) {
        k0 += wb_r[c] * ga[c];  k1 += wb_r[6 + c] * ga[c];  k2 += wb_r[12 + c] * ga[c];
        v0 += wbv_r[c] * ga[c]; v1 += wbv_r[6 + c] * ga[c]; v2 += wbv_r[12 + c] * ga[c];
      }
      kk[e][0] = k0; kk[e][1] = k1; kk[e][2] = k2;
      vv[e][0] = v0; vv[e][1] = v1; vv[e][2] = v2;
      km[0] = fmaxf(km[0], fabsf(k0));
      km[1] = fmaxf(km[1], fabsf(k1));
      km[2] = fmaxf(km[2], fabsf(k2));
    }
    unsigned* ktg = (unsigned*)ws + KT_U + b * 4096;
    ktg[4 * pp + 0] = h2_bits(__builtin_amdgcn_cvt_pkrtz(kk[0][0], kk[0][1]));
    ktg[4 * pp + 1] = h2_bits(__builtin_amdgcn_cvt_pkrtz(kk[0][2], 0.f));
    ktg[4 * pp + 2] = h2_bits(__builtin_amdgcn_cvt_pkrtz(kk[1][0], kk[1][1]));
    ktg[4 * pp + 3] = h2_bits(__builtin_amdgcn_cvt_pkrtz(kk[1][2], 0.f));
    unsigned* vtg = (unsigned*)ws + VT_U + b * 4096;
    vtg[0 * 1024 + pp] = h2_bits(__builtin_amdgcn_cvt_pkrtz(vv[0][0], vv[1][0]));
    vtg[1 * 1024 + pp] = h2_bits(__builtin_amdgcn_cvt_pkrtz(vv[0][1], vv[1][1]));
    vtg[2 * 1024 + pp] = h2_bits(__builtin_amdgcn_cvt_pkrtz(vv[0][2], vv[1][2]));
    vtg[3 * 1024 + pp] = h2_bits(__builtin_amdgcn_cvt_pkrtz(1.f, 1.f));

    #pragma unroll
    for (int j = 0; j < 3; j++) km[j] = wave_reduce_max(km[j]);
    if (lane == 0) { for (int j = 0; j < 3; j++) sred[wid * 3 + j] = km[j]; }
    __syncthreads();
    if (tid == 0) {
      for (int j = 0; j < 3; j++)
        ws[PBKM_OFF + (blk - 6) * 3 + j] =
          fmaxf(fmaxf(sred[j], sred[3 + j]), fmaxf(sred[6 + j], sred[9 + j]));
    }
  }
}

// ---------------------------------------------------------------- main ----
// 1024 blocks x 256 thr (4 waves). Block = 64 rows. Wave w: rows
// rp=w>>1 (2 row-tiles of 16), key-half kh=w&1 (64 chunks of 16 keys).
// Per chunk: 1 K-read + 1 V-read feed 2 score MFMAs + 2 PV MFMAs (dual
// accumulators per row-tile, register prefetch). Key-halves combined via
// LDS cross-buffer; k_inter/v_inter recomputed per block (lanes 0-17).
__global__ __launch_bounds__(256, 4)
void attn_kernel(const float* __restrict__ x,  const float* __restrict__ Wc,
                 const float* __restrict__ Wd, const float* __restrict__ lng,
                 const float* __restrict__ lnb,
                 const float* __restrict__ Wa, const float* __restrict__ Wav,
                 const float* __restrict__ Wpl, const float* __restrict__ bpl,
                 float* __restrict__ ws, float* __restrict__ yout)
{
  __shared__ __align__(16) unsigned kt[4224];  // 2048 keys x 2 dw; pad zeros @4096-97
  __shared__ __align__(16) unsigned vt[4224];  // 4 planes x 1028; pad zeros @4112-13
  __shared__ float4 cross[2][64];
  __shared__ float gis[18], kis[9], vis[9];
  const int tid  = threadIdx.x, blk = blockIdx.x;
  const int lane = tid & 63, w = tid >> 6;
  const int col  = lane & 15, hi4 = lane >> 4;
  const int rp   = w >> 1, kh = w & 1;
  const int rbase = blk * 64;
  const int b    = rbase >> 15;
  const int nb   = rbase & (N_PTS - 1);

  // ---- stage K/V tables ----
  {
    const uint4* ktg = (const uint4*)((const unsigned*)ws + KT_U + b * 4096);
    uint4* kt4 = (uint4*)kt;
    for (int i = tid; i < 1024; i += 256) kt4[i] = ktg[i];
    const uint2* vtg2 = (const uint2*)((const unsigned*)ws + VT_U + b * 4096);
    for (int i = tid; i < 2048; i += 256) {
      int pl = i >> 9, off = (i & 511) << 1;
      *(uint2*)&vt[pl * 1028 + off] = vtg2[i];
    }
    if (tid < 2) { kt[4096 + tid] = 0; vt[4112 + tid] = 0; }
  }
  // gis by lanes 0-17 (overlaps staging)
  if (tid < 18) {
    int c = tid / 3, m = tid % 3;
    float pl_ = bpl[m];
    #pragma unroll
    for (int k = 0; k < 3; k++)
      pl_ = fmaf(Wpl[m * 3 + k], ws[CS_OFF + k * 6 + c] * (1.f / LL), pl_);
    gis[c * 3 + m] = ws[W_OFF + (b * 3 + m) * 6 + c] / ws[MS_OFF + (b * 3 + m) * 2 + 1] + pl_;
  }
  __syncthreads();
  if (tid < 9) {
    int m = tid / 3, k = tid % 3;
    float s1 = 0.f, s2 = 0.f;
    #pragma unroll
    for (int c = 0; c < 6; c++) {
      float g = gis[c * 3 + k];
      s1 = fmaf(Wa [m * 6 + c], g, s1);
      s2 = fmaf(Wav[m * 6 + c], g, s2);
    }
    kis[m * 3 + k] = s1; vis[k * 3 + m] = s2;
  }

  // kmax from per-kvblock slots
  float km0 = 0.f, km1 = 0.f, km2 = 0.f;
  #pragma unroll
  for (int s = 0; s < 4; s++) {
    const float* pk = ws + PBKM_OFF + (b * 4 + s) * 3;
    km0 = fmaxf(km0, pk[0]); km1 = fmaxf(km1, pk[1]); km2 = fmaxf(km2, pk[2]);
  }

  // q for both row-tiles
  const int nA = nb + rp * 32 + col, nBr = nA + 16;
  const float* xb = x + (size_t)b * 6 * N_PTS;
  float q0A = 0, q1A = 0, q2A = 0, q0B = 0, q1B = 0, q2B = 0;
  #pragma unroll
  for (int c = 0; c < 6; c++) {
    float xvA = xb[c * N_PTS + nA], xvB = xb[c * N_PTS + nBr];
    q0A = fmaf(xvA, Wc[c], q0A); q1A = fmaf(xvA, Wc[6 + c], q1A); q2A = fmaf(xvA, Wc[12 + c], q2A);
    q0B = fmaf(xvB, Wc[c], q0B); q1B = fmaf(xvB, Wc[6 + c], q1B); q2B = fmaf(xvB, Wc[12 + c], q2B);
  }
  const float KS = 1.4426950408889634f * 0.57735026918962576f;  // log2e/sqrt(3)
  q0A *= KS; q1A *= KS; q2A *= KS; q0B *= KS; q1B *= KS; q2B *= KS;
  const float MpA = fabsf(q0A) * km0 + fabsf(q1A) * km1 + fabsf(q2A) * km2;
  const float MpB = fabsf(q0B) * km0 + fabsf(q1B) * km1 + fabsf(q2B) * km2;

  union U2 { uint2 u; f16x4 h; };
  U2 qbA, qbB;
  qbA.u.x = qbA.u.y = qbB.u.x = qbB.u.y = 0;
  if (hi4 == 0) {
    qbA.u.x = h2_bits(__builtin_amdgcn_cvt_pkrtz(q0A, q1A));
    qbA.u.y = h2_bits(__builtin_amdgcn_cvt_pkrtz(q2A, 0.f));
    qbB.u.x = h2_bits(__builtin_amdgcn_cvt_pkrtz(q0B, q1B));
    qbB.u.y = h2_bits(__builtin_amdgcn_cvt_pkrtz(q2B, 0.f));
  }
  f32x4 cbA = { -MpA, -MpA, -MpA, -MpA };
  f32x4 cbB = { -MpB, -MpB, -MpB, -MpB };
  f32x4 aA0 = {0,0,0,0}, aA1 = {0,0,0,0}, aB0 = {0,0,0,0}, aB1 = {0,0,0,0};

  unsigned ki_ = (hi4 == 0) ? (unsigned)(kh * 2048 + col * 2) : 4096u;
  const unsigned kd = (hi4 == 0) ? 32u : 0u;
  unsigned vi_ = (col < 4) ? (unsigned)(col * 1028 + kh * 512 + 2 * hi4) : 4112u;
  const unsigned vd = (col < 4) ? 8u : 0u;

  U2 Kc, Vc;
  Kc.u = *(const uint2*)&kt[ki_];
  Vc.u = *(const uint2*)&vt[vi_];

  #pragma unroll 4
  for (int i = 0; i < 64; i++) {
    ki_ += kd; vi_ += vd;
    U2 Kn, Vn;                              // prefetch (last iter reads pad, unused)
    Kn.u = *(const uint2*)&kt[ki_];
    Vn.u = *(const uint2*)&vt[vi_];
    f32x4 sA = __builtin_amdgcn_mfma_f32_16x16x16f16(Kc.h, qbA.h, cbA, 0, 0, 0);
    f32x4 sB = __builtin_amdgcn_mfma_f32_16x16x16f16(Kc.h, qbB.h, cbB, 0, 0, 0);
    float eA0 = __builtin_amdgcn_exp2f(sA[0]);
    float eA1 = __builtin_amdgcn_exp2f(sA[1]);
    float eA2 = __builtin_amdgcn_exp2f(sA[2]);
    float eA3 = __builtin_amdgcn_exp2f(sA[3]);
    float eB0 = __builtin_amdgcn_exp2f(sB[0]);
    float eB1 = __builtin_amdgcn_exp2f(sB[1]);
    float eB2 = __builtin_amdgcn_exp2f(sB[2]);
    float eB3 = __builtin_amdgcn_exp2f(sB[3]);
    U2 PA, PB;
    PA.u.x = h2_bits(__builtin_amdgcn_cvt_pkrtz(eA0, eA1));
    PA.u.y = h2_bits(__builtin_amdgcn_cvt_pkrtz(eA2, eA3));
    PB.u.x = h2_bits(__builtin_amdgcn_cvt_pkrtz(eB0, eB1));
    PB.u.y = h2_bits(__builtin_amdgcn_cvt_pkrtz(eB2, eB3));
    if (i & 1) {
      aA1 = __builtin_amdgcn_mfma_f32_16x16x16f16(Vc.h, PA.h, aA1, 0, 0, 0);
      aB1 = __builtin_amdgcn_mfma_f32_16x16x16f16(Vc.h, PB.h, aB1, 0, 0, 0);
    } else {
      aA0 = __builtin_amdgcn_mfma_f32_16x16x16f16(Vc.h, PA.h, aA0, 0, 0, 0);
      aB0 = __builtin_amdgcn_mfma_f32_16x16x16f16(Vc.h, PB.h, aB0, 0, 0, 0);
    }
    Kc = Kn; Vc = Vn;
  }

  if (hi4 == 0) {
    cross[kh][rp * 32 + col] =
      make_float4(aA0[0] + aA1[0], aA0[1] + aA1[1], aA0[2] + aA1[2], aA0[3] + aA1[3]);
    cross[kh][rp * 32 + 16 + col] =
      make_float4(aB0[0] + aB1[0], aB0[1] + aB1[1], aB0[2] + aB1[2], aB0[3] + aB1[3]);
  }
  __syncthreads();

  if (tid < 64) {
    const int ri = tid, n = nb + ri;
    float4 c0 = cross[0][ri], c1 = cross[1][ri];
    float w0 = c0.x + c1.x, w1 = c0.y + c1.y, w2 = c0.z + c1.z, dd = c0.w + c1.w;

    float a0 = 0, a1 = 0, a2 = 0;
    #pragma unroll
    for (int c = 0; c < 6; c++) {
      float xv = xb[c * N_PTS + n];
      a0 = fmaf(xv, Wc[c], a0); a1 = fmaf(xv, Wc[6 + c], a1); a2 = fmaf(xv, Wc[12 + c], a2);
    }
    a0 *= KS; a1 *= KS; a2 *= KS;

    float sk0 = a0 * kis[0] + a1 * kis[3] + a2 * kis[6];
    float sk1 = a0 * kis[1] + a1 * kis[4] + a2 * kis[7];
    float sk2 = a0 * kis[2] + a1 * kis[5] + a2 * kis[8];
    float mm  = fmaxf(fmaxf(sk0, sk1), sk2);
    float e0 = __builtin_amdgcn_exp2f(sk0 - mm);
    float e1 = __builtin_amdgcn_exp2f(sk1 - mm);
    float e2 = __builtin_amdgcn_exp2f(sk2 - mm);
    float rs = 1.f / (e0 + e1 + e2);
    float fi0 = (e0 * vis[0] + e1 * vis[3] + e2 * vis[6]) * rs;
    float fi1 = (e0 * vis[1] + e1 * vis[4] + e2 * vis[7]) * rs;
    float fi2 = (e0 * vis[2] + e1 * vis[5] + e2 * vis[8]) * rs;
    float rinv = 1.f / dd;
    float cf[6] = { fi0, fi1, fi2, w0 * rinv, w1 * rinv, w2 * rinv };

    float mu = (cf[0] + cf[1] + cf[2] + cf[3] + cf[4] + cf[5]) * (1.f / 6.f);
    float var = 0.f;
    #pragma unroll
    for (int i = 0; i < 6; i++) { float t = cf[i] - mu; var += t * t; }
    var *= (1.f / 6.f);
    float rn = rsqrtf(var + 1e-5f);
    float cfn[6];
    #pragma unroll
    for (int i = 0; i < 6; i++) cfn[i] = (cf[i] - mu) * rn * lng[i] + lnb[i];

    float v12[12];
    #pragma unroll
    for (int o = 0; o < 6; o++) {
      float s = 0.f;
      #pragma unroll
      for (int c = 0; c < 6; c++) s += Wd[o * 6 + c] * cfn[c];
      yout[(size_t)b * (6 * N_PTS) + o * N_PTS + n] = s;
      v12[o] = s; v12[6 + o] = s * s;
    }
    #pragma unroll
    for (int j = 0; j < 12; j++) v12[j] = wave_reduce_sum(v12[j]);
    if (tid == 0) {
      float* part = ws + PART_OFF + blk * 12;
      for (int j = 0; j < 12; j++) part[j] = v12[j];
    }
  }
}

// ------------------------------------------------------------- bn stats ---
__global__ __launch_bounds__(256)
void bnstats_kernel(const float* __restrict__ bng, const float* __restrict__ bnbt,
                    float* __restrict__ ws)
{
  __shared__ float cp[48];
  const int tid = threadIdx.x;
  const float* part = ws + PART_OFF;
  float v[12];
  #pragma unroll
  for (int j = 0; j < 12; j++)
    v[j] = part[tid * 12 + j] + part[(tid + 256) * 12 + j]
         + part[(tid + 512) * 12 + j] + part[(tid + 768) * 12 + j];
  #pragma unroll
  for (int j = 0; j < 12; j++) v[j] = wave_reduce_sum(v[j]);
  const int lane = tid & 63, wid = tid >> 6;
  if (lane == 0) { for (int j = 0; j < 12; j++) cp[wid * 12 + j] = v[j]; }
  __syncthreads();
  if (tid == 0) {
    const float inv = 1.f / 65536.f;   // B * N
    for (int o = 0; o < 6; o++) {
      float s1 = cp[o] + cp[12 + o] + cp[24 + o] + cp[36 + o];
      float s2 = cp[6 + o] + cp[18 + o] + cp[30 + o] + cp[42 + o];
      float mean = s1 * inv;
      float varr = s2 * inv - mean * mean;
      float sc = bng[o] * rsqrtf(varr + 1e-5f);
      ws[BNS_OFF + o] = sc;
      ws[BNB_OFF + o] = bnbt[o] - mean * sc;
    }
  }
}

// ------------------------------------------------------------- finalize ---
__global__ __launch_bounds__(256)
void final_kernel(const float* __restrict__ x, const float* __restrict__ ws,
                  float* __restrict__ out)
{
  const int i = blockIdx.x * 256 + threadIdx.x;   // 393216 total
  const int ch = (i >> 15) % 6;
  float v = out[i] * ws[BNS_OFF + ch] + ws[BNB_OFF + ch] + x[i];
  out[i] = v >= 0.f ? v : 0.2f * v;
}

// ---------------------------------------------------------------- launch --
extern "C" void kernel_launch(void* const* d_in, const int* in_sizes, int n_in,
                              void* d_out, int out_size, void* d_ws, size_t ws_size,
                              hipStream_t stream)
{
  const float* x      = (const float*)d_in[0];
  const float* curves = (const float*)d_in[1];
  const float* Wa     = (const float*)d_in[2];
  const float* Wav    = (const float*)d_in[3];
  const float* Wb     = (const float*)d_in[4];
  const float* Wbv    = (const float*)d_in[5];
  const float* Wc     = (const float*)d_in[6];
  const float* Wd     = (const float*)d_in[7];
  const float* bng    = (const float*)d_in[8];
  const float* bnbt   = (const float*)d_in[9];
  const float* Watt   = (const float*)d_in[10];
  const float* lng    = (const float*)d_in[11];
  const float* lnbt   = (const float*)d_in[12];
  const float* Wpl    = (const float*)d_in[13];
  const float* bpl    = (const float*)d_in[14];
  const float* Wpn    = (const float*)d_in[15];
  const float* bpn    = (const float*)d_in[16];
  float* out = (float*)d_out;
  float* ws  = (float*)d_ws;

  prep_kernel<<<14, 256, 0, stream>>>(curves, Watt, Wb, Wbv, Wpn, bpn, ws);
  attn_kernel<<<1024, 256, 0, stream>>>(x, Wc, Wd, lng, lnbt,
                                        Wa, Wav, Wpl, bpl, ws, out);
  bnstats_kernel<<<1, 256, 0, stream>>>(bng, bnbt, ws);
  final_kernel<<<1536, 256, 0, stream>>>(x, ws, out);
}